// Round 10
// baseline (6724.548 us; speedup 1.0000x reference)
//
#include <hip/hip_runtime.h>
#include <stdint.h>

#define BATCH 32
#define SEQ   128       // S == T == 128
#define HID   512
#define VTOK  32000

typedef unsigned short u16;
typedef unsigned int   u32;
typedef unsigned long long u64;
typedef float    f32x4  __attribute__((ext_vector_type(4)));
typedef short    short8 __attribute__((ext_vector_type(8)));

__device__ __forceinline__ u16 f2bf(float f) {
    u32 u = __builtin_bit_cast(u32, f);
    return (u16)((u + 0x7FFFu + ((u >> 16) & 1u)) >> 16);
}
__device__ __forceinline__ float bf2f(u16 v) {
    u32 u = ((u32)v) << 16; return __builtin_bit_cast(float, u);
}
__device__ __forceinline__ float fexp2(float x) { return __builtin_amdgcn_exp2f(x); }
__device__ __forceinline__ float frcp(float x)  { return __builtin_amdgcn_rcpf(x); }
__device__ __forceinline__ float sigmoid_f(float x) {
    return frcp(1.f + fexp2(-1.442695040888963f * x));
}
__device__ __forceinline__ float tanh_f(float x) {
    return 1.f - 2.f * frcp(1.f + fexp2(2.885390081777927f * x));
}

// ---- LLC-coherent (sc1) relaxed atomics ----
__device__ __forceinline__ u32 ld_sc1_u32(const u32* p) {
    return __hip_atomic_load(p, __ATOMIC_RELAXED, __HIP_MEMORY_SCOPE_AGENT);
}
__device__ __forceinline__ void st_sc1_u32(u32* p, u32 v) {
    __hip_atomic_store(p, v, __ATOMIC_RELAXED, __HIP_MEMORY_SCOPE_AGENT);
}
__device__ __forceinline__ u64 ld_sc1_u64(const u64* p) {
    return __hip_atomic_load(p, __ATOMIC_RELAXED, __HIP_MEMORY_SCOPE_AGENT);
}
__device__ __forceinline__ short8 ldA(const u64* base) {
    union { u64 q[2]; short8 s; } u;
    u.q[0] = ld_sc1_u64(base);
    u.q[1] = ld_sc1_u64(base + 1);
    return u.s;
}

// ---- symmetric all-report/all-poll barrier over 32 WGs ----
// WG w stores gen to flags[w*16] (64B slot); 32 lanes each poll one flag.
// vmcnt(0) drain before syncthreads => all this WG's sc1 data is at LLC
// before its flag store (scheme proven correct, absmax 0.0, rounds 6-9).
__device__ __forceinline__ void gbar32(u32* flags, u32 gen) {
    asm volatile("s_waitcnt vmcnt(0)" ::: "memory");
    __syncthreads();
    if (threadIdx.x == 0) st_sc1_u32(flags + (u32)blockIdx.x * 16, gen);
    const int i = threadIdx.x;
    if (i < 32 && i != (int)blockIdx.x) {
        while (ld_sc1_u32(flags + i * 16) < gen) {}
    }
    __syncthreads();
}

// ---------------- prep kernels ----------------

// f32 [K,N] -> bf16 [N,K]
__global__ __launch_bounds__(256) void transpose_cvt(
    const float* __restrict__ src, u16* __restrict__ dst, int K, int N)
{
    __shared__ float tile[32][33];
    const int n0 = blockIdx.x * 32, k0 = blockIdx.y * 32;
    const int tx = threadIdx.x & 31, ty = threadIdx.x >> 5;
    #pragma unroll
    for (int j = 0; j < 32; j += 8)
        tile[ty + j][tx] = src[(size_t)(k0 + ty + j) * N + n0 + tx];
    __syncthreads();
    #pragma unroll
    for (int j = 0; j < 32; j += 8)
        dst[(size_t)(n0 + ty + j) * K + k0 + tx] = f2bf(tile[tx][ty + j]);
}

__global__ __launch_bounds__(256) void cvt_f32_bf16(
    const float* __restrict__ src, u16* __restrict__ dst)
{
    const size_t i = ((size_t)blockIdx.x * 256 + threadIdx.x) * 8;
    float4 v0 = *(const float4*)(src + i);
    float4 v1 = *(const float4*)(src + i + 4);
    uint4 pk;
    pk.x = (u32)f2bf(v0.x) | ((u32)f2bf(v0.y) << 16);
    pk.y = (u32)f2bf(v0.z) | ((u32)f2bf(v0.w) << 16);
    pk.z = (u32)f2bf(v1.x) | ((u32)f2bf(v1.y) << 16);
    pk.w = (u32)f2bf(v1.z) | ((u32)f2bf(v1.w) << 16);
    *(uint4*)(dst + i) = pk;
}

__global__ __launch_bounds__(128) void gather_emb_bf16(
    const int* __restrict__ idx, const float* __restrict__ emb, u16* __restrict__ out)
{
    const int r = blockIdx.x;
    const int token = idx[r];
    const int i = threadIdx.x * 4;
    float4 v = *(const float4*)(emb + (size_t)token * 512 + i);
    uint2 pk;
    pk.x = (u32)f2bf(v.x) | ((u32)f2bf(v.y) << 16);
    pk.y = (u32)f2bf(v.z) | ((u32)f2bf(v.w) << 16);
    *(uint2*)(out + (size_t)r * 512 + i) = pk;
}

// zero h (both parities, 16384 u32) + flag blocks (1024 u32)
__global__ __launch_bounds__(512) void init_state(u32* hg, u32* bar)
{
    const int i = blockIdx.x * 512 + threadIdx.x;
    hg[i] = 0u;
    if (blockIdx.x < 2) bar[blockIdx.x * 512 + threadIdx.x] = 0u;
}

// ---------------- MFMA GEMM:  C[M,N](f32) = A[M,K](bf16) * BT[N,K](bf16) + bias ----------------
__global__ __launch_bounds__(256) void gemm_bf16(
    const u16* __restrict__ A, const u16* __restrict__ BT,
    const float* __restrict__ bias, float* __restrict__ C,
    int M, int N, int K)
{
    __shared__ __align__(16) u16 As[128][40];
    __shared__ __align__(16) u16 Bs[128][40];
    const int tid  = threadIdx.x;
    const int lane = tid & 63, wave = tid >> 6;
    const int wm = (wave & 1) * 64, wn = (wave >> 1) * 64;
    const int lrow = lane & 15, lk = (lane >> 4) * 8;
    const int srow = tid >> 2, skof = (tid & 3) * 8;
    const size_t K_ = (size_t)K;
    const u16* Ag = A + ((size_t)blockIdx.y * 128 + srow) * K_ + skof;
    const u16* Bg = BT + ((size_t)blockIdx.x * 128 + srow) * K_ + skof;
    f32x4 acc[4][4] = {};
    for (int k0 = 0; k0 < K; k0 += 32) {
        uint4 a0 = *(const uint4*)(Ag + k0);
        uint4 a1 = *(const uint4*)(Ag + 64 * K_ + k0);
        uint4 b0 = *(const uint4*)(Bg + k0);
        uint4 b1 = *(const uint4*)(Bg + 64 * K_ + k0);
        __syncthreads();
        *(uint4*)&As[srow][skof]      = a0;
        *(uint4*)&As[srow + 64][skof] = a1;
        *(uint4*)&Bs[srow][skof]      = b0;
        *(uint4*)&Bs[srow + 64][skof] = b1;
        __syncthreads();
        short8 af[4], bf[4];
        #pragma unroll
        for (int i = 0; i < 4; ++i) af[i] = *(const short8*)&As[wm + i * 16 + lrow][lk];
        #pragma unroll
        for (int j = 0; j < 4; ++j) bf[j] = *(const short8*)&Bs[wn + j * 16 + lrow][lk];
        #pragma unroll
        for (int i = 0; i < 4; ++i)
            #pragma unroll
            for (int j = 0; j < 4; ++j)
                acc[i][j] = __builtin_amdgcn_mfma_f32_16x16x32_bf16(af[i], bf[j], acc[i][j], 0, 0, 0);
    }
    const int crow0 = blockIdx.y * 128 + wm + (lane >> 4) * 4;
    const int ccol0 = blockIdx.x * 128 + wn + (lane & 15);
    #pragma unroll
    for (int j = 0; j < 4; ++j) {
        const float bv = bias ? bias[ccol0 + j * 16] : 0.f;
        #pragma unroll
        for (int i = 0; i < 4; ++i)
            #pragma unroll
            for (int rr = 0; rr < 4; ++rr)
                C[(size_t)(crow0 + i * 16 + rr) * N + (ccol0 + j * 16)] = acc[i][j][rr] + bv;
    }
}

// ============ persistent encoder: 32 WGs, LDS-resident weight slices ============
__global__ __launch_bounds__(512) void enc_coop(
    const float* __restrict__ gx, const u16* __restrict__ Urz, const u16* __restrict__ Un,
    const float* __restrict__ brz, const float* __restrict__ bn,
    u32* __restrict__ hg, u32* __restrict__ rhg, u32* __restrict__ zg,
    u16* __restrict__ enc_hs, u16* __restrict__ spack,
    u32* __restrict__ flags)
{
    const int w = blockIdx.x, tid = threadIdx.x;
    const int v = tid >> 6, lane = tid & 63;
    const int nl = lane & 15, kq = lane >> 4;
    __shared__ __align__(16) u16 UrzS[32][520];   // cols w*32 .. w*32+31
    __shared__ __align__(16) u16 UnS[16][520];    // cols w*16 .. w*16+15
    for (int idx = tid; idx < 32 * 64; idx += 512) {
        const int r = idx >> 6, c = idx & 63;
        *(uint4*)&UrzS[r][c * 8] = *(const uint4*)(Urz + (size_t)(w * 32 + r) * 512 + c * 8);
    }
    for (int idx = tid; idx < 16 * 64; idx += 512) {
        const int r = idx >> 6, c = idx & 63;
        *(uint4*)&UnS[r][c * 8] = *(const uint4*)(Un + (size_t)(w * 16 + r) * 512 + c * 8);
    }
    __syncthreads();
    const u64* rq = (const u64*)rhg;
    for (int t = 0; t < SEQ; ++t) {
        const u32* hgA = hg + (t & 1) * 8192;
        u32*       hgW = hg + ((t + 1) & 1) * 8192;
        const u64* hq  = (const u64*)hgA;
        // ---- E1: h@Urz (waves 0..3: bt = v&1, tile = v>>1) ----
        if (v < 4) {
            const int bt = v & 1, tl = v >> 1;
            const int n = w * 32 + tl * 16 + nl;
            const int brow = bt * 16 + nl;
            float gxr_pf[4]; u32 hv_pf[4];
            #pragma unroll
            for (int rr = 0; rr < 4; ++rr) {
                const int b = bt * 16 + kq * 4 + rr;
                gxr_pf[rr] = gx[((size_t)(b * SEQ + t)) * 1536 + n];
                if (n < 512) hv_pf[rr] = ld_sc1_u32(hgA + b * 256 + (n >> 1));
            }
            const u16* wl = &UrzS[tl * 16 + nl][0];
            f32x4 acc = {0.f, 0.f, 0.f, 0.f};
            #pragma unroll
            for (int k0 = 0; k0 < 512; k0 += 32) {
                short8 af = ldA(hq + brow * 128 + (k0 >> 2) + kq * 2);
                short8 bf = *(const short8*)(wl + k0 + kq * 8);
                acc = __builtin_amdgcn_mfma_f32_16x16x32_bf16(af, bf, acc, 0, 0, 0);
            }
            if (n < 512) {               // r gate -> rh
                u32 pk[4];
                #pragma unroll
                for (int rr = 0; rr < 4; ++rr) {
                    const float r = sigmoid_f(gxr_pf[rr] + acc[rr] + brz[n]);
                    const float hold = bf2f((u16)((n & 1) ? (hv_pf[rr] >> 16) : (hv_pf[rr] & 0xFFFF)));
                    pk[rr] = (u32)f2bf(r * hold);
                }
                #pragma unroll
                for (int rr = 0; rr < 4; ++rr) {
                    u32 oth = (u32)__shfl_xor((int)pk[rr], 1);
                    if ((n & 1) == 0) {
                        const int b = bt * 16 + kq * 4 + rr;
                        st_sc1_u32(rhg + b * 256 + (n >> 1), (pk[rr] & 0xFFFF) | (oth << 16));
                    }
                }
            } else {                     // z gate
                #pragma unroll
                for (int rr = 0; rr < 4; ++rr) {
                    const int b = bt * 16 + kq * 4 + rr;
                    const float z = sigmoid_f(gxr_pf[rr] + acc[rr] + brz[n]);
                    st_sc1_u32(zg + (n - 512) * 32 + b, __float_as_uint(z));
                }
            }
        }
        gbar32(flags, (u32)(2 * t + 1));
        // ---- E2: (r*h)@Un, h update (waves 0..1) ----
        if (v < 2) {
            const int bt = v;
            const int n = w * 16 + nl;
            const int brow = bt * 16 + nl;
            float gxr_pf[4]; u32 hv_pf[4], zv_pf[4];
            #pragma unroll
            for (int rr = 0; rr < 4; ++rr) {
                const int b = bt * 16 + kq * 4 + rr;
                gxr_pf[rr] = gx[((size_t)(b * SEQ + t)) * 1536 + 1024 + n];
                hv_pf[rr] = ld_sc1_u32(hgA + b * 256 + (n >> 1));
                zv_pf[rr] = ld_sc1_u32(zg + n * 32 + b);
            }
            const u16* wl = &UnS[nl][0];
            f32x4 acc = {0.f, 0.f, 0.f, 0.f};
            #pragma unroll
            for (int k0 = 0; k0 < 512; k0 += 32) {
                short8 af = ldA(rq + brow * 128 + (k0 >> 2) + kq * 2);
                short8 bf = *(const short8*)(wl + k0 + kq * 8);
                acc = __builtin_amdgcn_mfma_f32_16x16x32_bf16(af, bf, acc, 0, 0, 0);
            }
            u32 pk[4];
            #pragma unroll
            for (int rr = 0; rr < 4; ++rr) {
                const int b = bt * 16 + kq * 4 + rr;
                const float nn = tanh_f(gxr_pf[rr] + acc[rr] + bn[n]);
                const float z = __uint_as_float(zv_pf[rr]);
                const float hold = bf2f((u16)((n & 1) ? (hv_pf[rr] >> 16) : (hv_pf[rr] & 0xFFFF)));
                const float hn = (1.f - z) * hold + z * nn;
                const u16 hb = f2bf(hn);
                pk[rr] = (u32)hb;
                enc_hs[((size_t)(b * SEQ + t)) * 512 + n] = hb;
                spack[(((size_t)b * 16 + (t >> 3)) * 512 + n) * 8 + (t & 7)] = hb;
            }
            #pragma unroll
            for (int rr = 0; rr < 4; ++rr) {
                u32 oth = (u32)__shfl_xor((int)pk[rr], 1);
                if ((n & 1) == 0) {
                    const int b = bt * 16 + kq * 4 + rr;
                    st_sc1_u32(hgW + b * 256 + (n >> 1), (pk[rr] & 0xFFFF) | (oth << 16));
                }
            }
        }
        gbar32(flags, (u32)(2 * t + 2));
    }
}

// ============ persistent decoder: 32 WGs, LDS-resident weight slices ============
__global__ __launch_bounds__(512) void dec_coop(
    const float* __restrict__ gxe, const u16* __restrict__ wh_bf, const u16* __restrict__ spack,
    const float* __restrict__ attn_v, const float* __restrict__ brz, const float* __restrict__ bn,
    const u16* __restrict__ Urz, const u16* __restrict__ Ws,
    const u16* __restrict__ WxC, const u16* __restrict__ Un,
    u32* __restrict__ hg, u32* __restrict__ rhg, u32* __restrict__ ctxg,
    u32* __restrict__ zg, u32* __restrict__ gg, u32* __restrict__ aWsg,
    u16* __restrict__ hctx, u32* __restrict__ flags)
{
    const int w = blockIdx.x, tid = threadIdx.x;
    const int v = tid >> 6, lane = tid & 63;
    const int nl = lane & 15, kq = lane >> 4;
    __shared__ __align__(16) u16 UWsS[48][520];   // cols w*48.. of [Urz|Ws] concat
    __shared__ __align__(16) u16 WxCS[48][520];   // cols w*48.. of WxC
    __shared__ __align__(16) u16 UnS2[16][520];   // cols w*16.. of Un
    __shared__ float hWsL[4 * 132], redE[512], attnL[128];
    __shared__ u16 ctxL[512];
    for (int idx = tid; idx < 48 * 64; idx += 512) {
        const int r = idx >> 6, c = idx & 63;
        const int gcol = w * 48 + r;
        const u16* s0 = (gcol < 1024 ? Urz + (size_t)gcol * 512
                                     : Ws + (size_t)(gcol - 1024) * 512) + c * 8;
        *(uint4*)&UWsS[r][c * 8] = *(const uint4*)s0;
        *(uint4*)&WxCS[r][c * 8] = *(const uint4*)(WxC + (size_t)gcol * 512 + c * 8);
    }
    for (int idx = tid; idx < 16 * 64; idx += 512) {
        const int r = idx >> 6, c = idx & 63;
        *(uint4*)&UnS2[r][c * 8] = *(const uint4*)(Un + (size_t)(w * 16 + r) * 512 + c * 8);
    }
    __syncthreads();
    const u64* rq = (const u64*)rhg;
    const u64* cq = (const u64*)ctxg;
    for (int t = 0; t < SEQ; ++t) {
        const u32* hgA = hg + (t & 1) * 8192;
        u32*       hgW = hg + ((t + 1) & 1) * 8192;
        const u64* hq  = (const u64*)hgA;
        f32x4 aPk = {0.f, 0.f, 0.f, 0.f};
        // ---- P1: h@[Urz | Ws] (waves 0..5: bt = v&1, tile = v>>1) ----
        if (v < 6) {
            const int bt = v & 1, tl = v >> 1;
            const int n = w * 48 + tl * 16 + nl;
            const int brow = bt * 16 + nl;
            const u16* wl = &UWsS[tl * 16 + nl][0];
            f32x4 acc = {0.f, 0.f, 0.f, 0.f};
            #pragma unroll
            for (int k0 = 0; k0 < 512; k0 += 32) {
                short8 af = ldA(hq + brow * 128 + (k0 >> 2) + kq * 2);
                short8 bf = *(const short8*)(wl + k0 + kq * 8);
                acc = __builtin_amdgcn_mfma_f32_16x16x32_bf16(af, bf, acc, 0, 0, 0);
            }
            if (n < 1024) {
                aPk = acc;               // persists in regs to P3 (same lane, same n,b)
            } else {
                #pragma unroll
                for (int rr = 0; rr < 4; ++rr) {
                    const int b = bt * 16 + kq * 4 + rr;
                    st_sc1_u32(aWsg + (n - 1024) * 32 + b, __float_as_uint(acc[rr]));
                }
            }
        }
        gbar32(flags, (u32)(4 * t + 1));
        // ---- P2: attention (all 32 WGs, b = w) ----
        {
            const int b = w;
            hWsL[(tid >> 7) * 132 + (tid & 127)] = __uint_as_float(ld_sc1_u32(aWsg + tid * 32 + b));
            __syncthreads();
            {
                const int s = tid >> 2, q = tid & 3;
                const u16* whr = wh_bf + ((size_t)(b * SEQ + s)) * 512 + q * 128;
                const float* avq = attn_v + q * 128;
                const float* hwq = &hWsL[q * 132];
                float e = 0.f;
                #pragma unroll 4
                for (int i = 0; i < 128; i += 8) {
                    uint4 wv = *(const uint4*)(whr + i);
                    float4 h0 = *(const float4*)(hwq + i);
                    float4 h1 = *(const float4*)(hwq + i + 4);
                    float4 v0 = *(const float4*)(avq + i);
                    float4 v1 = *(const float4*)(avq + i + 4);
                    e += v0.x * tanh_f(bf2f((u16)(wv.x & 0xFFFF)) + h0.x)
                       + v0.y * tanh_f(bf2f((u16)(wv.x >> 16))    + h0.y)
                       + v0.z * tanh_f(bf2f((u16)(wv.y & 0xFFFF)) + h0.z)
                       + v0.w * tanh_f(bf2f((u16)(wv.y >> 16))    + h0.w)
                       + v1.x * tanh_f(bf2f((u16)(wv.z & 0xFFFF)) + h1.x)
                       + v1.y * tanh_f(bf2f((u16)(wv.z >> 16))    + h1.y)
                       + v1.z * tanh_f(bf2f((u16)(wv.w & 0xFFFF)) + h1.z)
                       + v1.w * tanh_f(bf2f((u16)(wv.w >> 16))    + h1.w);
                }
                redE[tid] = e;
            }
            __syncthreads();
            if (tid < 64) {
                float e0 = redE[4 * tid] + redE[4 * tid + 1] + redE[4 * tid + 2] + redE[4 * tid + 3];
                float e1 = redE[4 * (tid + 64)] + redE[4 * (tid + 64) + 1]
                         + redE[4 * (tid + 64) + 2] + redE[4 * (tid + 64) + 3];
                float m = fmaxf(e0, e1);
                for (int o = 32; o >= 1; o >>= 1) m = fmaxf(m, __shfl_xor(m, o));
                float p0 = fexp2((e0 - m) * 1.442695040888963f);
                float p1 = fexp2((e1 - m) * 1.442695040888963f);
                float ss = p0 + p1;
                for (int o = 32; o >= 1; o >>= 1) ss += __shfl_xor(ss, o);
                const float inv = frcp(ss);
                attnL[tid]      = p0 * inv;
                attnL[tid + 64] = p1 * inv;
            }
            __syncthreads();
            {
                const int d = tid;
                float cv = 0.f;
                const u16* sp = spack + ((size_t)b * 16 * 512 + d) * 8;
                #pragma unroll 4
                for (int sb = 0; sb < 16; ++sb) {
                    uint4 sv = *(const uint4*)(sp + (size_t)sb * 4096);
                    const float* al = &attnL[sb * 8];
                    cv += al[0] * bf2f((u16)(sv.x & 0xFFFF)) + al[1] * bf2f((u16)(sv.x >> 16))
                        + al[2] * bf2f((u16)(sv.y & 0xFFFF)) + al[3] * bf2f((u16)(sv.y >> 16))
                        + al[4] * bf2f((u16)(sv.z & 0xFFFF)) + al[5] * bf2f((u16)(sv.z >> 16))
                        + al[6] * bf2f((u16)(sv.w & 0xFFFF)) + al[7] * bf2f((u16)(sv.w >> 16));
                }
                const u16 cb = f2bf(cv);
                ctxL[d] = cb;
                hctx[((size_t)(b * SEQ + t)) * 1024 + 512 + d] = cb;
            }
            __syncthreads();
            if (tid < 256) {
                u32 pk = (u32)ctxL[2 * tid] | ((u32)ctxL[2 * tid + 1] << 16);
                st_sc1_u32(ctxg + b * 256 + tid, pk);
            }
        }
        gbar32(flags, (u32)(4 * t + 2));
        // ---- P3: ctx@WxC + gates (waves 0..5; aPk from P1) ----
        if (v < 6) {
            const int bt = v & 1, tl = v >> 1;
            const int n = w * 48 + tl * 16 + nl;
            const int brow = bt * 16 + nl;
            float gxr_pf[4]; u32 hv_pf[4];
            #pragma unroll
            for (int rr = 0; rr < 4; ++rr) {
                const int b = bt * 16 + kq * 4 + rr;
                gxr_pf[rr] = gxe[((size_t)(b * SEQ + t)) * 1536 + n];
                if (n < 512) hv_pf[rr] = ld_sc1_u32(hgA + b * 256 + (n >> 1));
            }
            const u16* wl = &WxCS[tl * 16 + nl][0];
            f32x4 acc = {0.f, 0.f, 0.f, 0.f};
            #pragma unroll
            for (int k0 = 0; k0 < 512; k0 += 32) {
                short8 af = ldA(cq + brow * 128 + (k0 >> 2) + kq * 2);
                short8 bf = *(const short8*)(wl + k0 + kq * 8);
                acc = __builtin_amdgcn_mfma_f32_16x16x32_bf16(af, bf, acc, 0, 0, 0);
            }
            if (n < 512) {               // r gate -> rh
                u32 pk[4];
                #pragma unroll
                for (int rr = 0; rr < 4; ++rr) {
                    const float r = sigmoid_f(gxr_pf[rr] + acc[rr] + aPk[rr] + brz[n]);
                    const float hold = bf2f((u16)((n & 1) ? (hv_pf[rr] >> 16) : (hv_pf[rr] & 0xFFFF)));
                    pk[rr] = (u32)f2bf(r * hold);
                }
                #pragma unroll
                for (int rr = 0; rr < 4; ++rr) {
                    u32 oth = (u32)__shfl_xor((int)pk[rr], 1);
                    if ((n & 1) == 0) {
                        const int b = bt * 16 + kq * 4 + rr;
                        st_sc1_u32(rhg + b * 256 + (n >> 1), (pk[rr] & 0xFFFF) | (oth << 16));
                    }
                }
            } else if (n < 1024) {       // z gate
                #pragma unroll
                for (int rr = 0; rr < 4; ++rr) {
                    const int b = bt * 16 + kq * 4 + rr;
                    const float z = sigmoid_f(gxr_pf[rr] + acc[rr] + aPk[rr] + brz[n]);
                    st_sc1_u32(zg + (n - 512) * 32 + b, __float_as_uint(z));
                }
            } else {                     // n-gate pre-activation
                #pragma unroll
                for (int rr = 0; rr < 4; ++rr) {
                    const int b = bt * 16 + kq * 4 + rr;
                    st_sc1_u32(gg + (n - 1024) * 32 + b, __float_as_uint(gxr_pf[rr] + acc[rr]));
                }
            }
        }
        gbar32(flags, (u32)(4 * t + 3));
        // ---- P4: (r*h)@Un, h update (waves 0..1) ----
        if (v < 2) {
            const int bt = v;
            const int n = w * 16 + nl;
            const int brow = bt * 16 + nl;
            u32 gv_pf[4], zv_pf[4], hv_pf[4];
            #pragma unroll
            for (int rr = 0; rr < 4; ++rr) {
                const int b = bt * 16 + kq * 4 + rr;
                gv_pf[rr] = ld_sc1_u32(gg + n * 32 + b);
                zv_pf[rr] = ld_sc1_u32(zg + n * 32 + b);
                hv_pf[rr] = ld_sc1_u32(hgA + b * 256 + (n >> 1));
            }
            const u16* wl = &UnS2[nl][0];
            f32x4 acc = {0.f, 0.f, 0.f, 0.f};
            #pragma unroll
            for (int k0 = 0; k0 < 512; k0 += 32) {
                short8 af = ldA(rq + brow * 128 + (k0 >> 2) + kq * 2);
                short8 bf = *(const short8*)(wl + k0 + kq * 8);
                acc = __builtin_amdgcn_mfma_f32_16x16x32_bf16(af, bf, acc, 0, 0, 0);
            }
            u32 pk[4];
            #pragma unroll
            for (int rr = 0; rr < 4; ++rr) {
                const int b = bt * 16 + kq * 4 + rr;
                const float nn = tanh_f(__uint_as_float(gv_pf[rr]) + acc[rr] + bn[n]);
                const float z = __uint_as_float(zv_pf[rr]);
                const float hold = bf2f((u16)((n & 1) ? (hv_pf[rr] >> 16) : (hv_pf[rr] & 0xFFFF)));
                const float hn = (1.f - z) * hold + z * nn;
                const u16 hb = f2bf(hn);
                pk[rr] = (u32)hb;
                hctx[((size_t)(b * SEQ + t)) * 1024 + n] = hb;
            }
            #pragma unroll
            for (int rr = 0; rr < 4; ++rr) {
                u32 oth = (u32)__shfl_xor((int)pk[rr], 1);
                if ((n & 1) == 0) {
                    const int b = bt * 16 + kq * 4 + rr;
                    st_sc1_u32(hgW + b * 256 + (n >> 1), (pk[rr] & 0xFFFF) | (oth << 16));
                }
            }
        }
        gbar32(flags, (u32)(4 * t + 4));
    }
}

// ---------------- log_softmax: 2-pass (online max+sum), in-place on [4096, 32000] ----------------
__global__ __launch_bounds__(256) void log_softmax_rows(float* __restrict__ out)
{
    const int row = blockIdx.x, tid = threadIdx.x;
    float* p = out + (size_t)row * VTOK;
    __shared__ float rbM[4], rbS[4];
    const float L2E = 1.442695040888963f;
    float m = -3.0e38f, s = 0.f;
    for (int i = tid * 4; i < VTOK; i += 1024) {
        float4 v = *(const float4*)(p + i);
        float lm = fmaxf(fmaxf(v.x, v.y), fmaxf(v.z, v.w));
        float nm = fmaxf(m, lm);
        s = s * fexp2((m - nm) * L2E)
          + fexp2((v.x - nm) * L2E) + fexp2((v.y - nm) * L2E)
          + fexp2((v.z - nm) * L2E) + fexp2((v.w - nm) * L2E);
        m = nm;
    }
    for (int o = 32; o >= 1; o >>= 1) {
        float om = __shfl_xor(m, o), os = __shfl_xor(s, o);
        float nm = fmaxf(m, om);
        s = s * fexp2((m - nm) * L2E) + os * fexp2((om - nm) * L2E);
        m = nm;
    }
    if ((tid & 63) == 0) { rbM[tid >> 6] = m; rbS[tid >> 6] = s; }
    __syncthreads();
    {
        float fm = fmaxf(fmaxf(rbM[0], rbM[1]), fmaxf(rbM[2], rbM[3]));
        float fs = rbS[0] * fexp2((rbM[0] - fm) * L2E) + rbS[1] * fexp2((rbM[1] - fm) * L2E)
                 + rbS[2] * fexp2((rbM[2] - fm) * L2E) + rbS[3] * fexp2((rbM[3] - fm) * L2E);
        m = fm; s = fs;
    }
    const float lse = m + __builtin_amdgcn_logf(s) * 0.6931471805599453f;
    for (int i = tid * 4; i < VTOK; i += 1024) {
        float4 v = *(const float4*)(p + i);
        v.x -= lse; v.y -= lse; v.z -= lse; v.w -= lse;
        *(float4*)(p + i) = v;
    }
}

// ---------------- host launcher ----------------
extern "C" void kernel_launch(void* const* d_in, const int* in_sizes, int n_in,
                              void* d_out, int out_size, void* d_ws, size_t ws_size,
                              hipStream_t stream)
{
    (void)in_sizes; (void)n_in; (void)out_size; (void)ws_size;
    const int*   src       = (const int*)  d_in[0];
    const int*   tgt       = (const int*)  d_in[1];
    const float* enc_embed = (const float*)d_in[2];
    const float* enc_Wx    = (const float*)d_in[3];
    const float* enc_bx    = (const float*)d_in[4];
    const float* enc_Urz   = (const float*)d_in[5];
    const float* enc_brz   = (const float*)d_in[6];
    const float* enc_Un    = (const float*)d_in[7];
    const float* enc_bn    = (const float*)d_in[8];
    const float* dec_embed = (const float*)d_in[9];
    const float* dec_Wx    = (const float*)d_in[10];
    const float* dec_bx    = (const float*)d_in[11];
    const float* dec_Urz   = (const float*)d_in[12];
    const float* dec_brz   = (const float*)d_in[13];
    const float* dec_Un    = (const float*)d_in[14];
    const float* dec_bn    = (const float*)d_in[15];
    const float* attn_Wh   = (const float*)d_in[16];
    const float* attn_Ws   = (const float*)d_in[17];
    const float* attn_v    = (const float*)d_in[18];
    const float* out_W     = (const float*)d_in[19];
    const float* out_b     = (const float*)d_in[20];

    // --- scratch in d_out (524,288,000 B); all dead before the final GEMM overwrites ---
    char* ob = (char*)d_out;
    float* gx_enc   = (float*)(ob + 0);              // 25165824
    float* gxe_dec  = (float*)(ob + 25165824);       // 25165824
    float* wh_enc   = (float*)(ob + 50331648);       // 8388608
    u16*   Aenc     = (u16*)(ob + 58720256);         // 4194304
    u16*   Adec     = (u16*)(ob + 62914560);         // 4194304
    u16*   enc_hs   = (u16*)(ob + 67108864);         // 4194304
    u16*   spack    = (u16*)(ob + 71303168);         // 4194304
    u16*   wh_bf    = (u16*)(ob + 75497472);         // 4194304
    u16*   encWxT   = (u16*)(ob + 79691776);         // 1572864
    u16*   decWxET  = (u16*)(ob + 81264640);         // 1572864
    u16*   WhT      = (u16*)(ob + 82837504);         // 524288
    u16*   UrzET    = (u16*)(ob + 83361792);         // 1048576
    u16*   UnET     = (u16*)(ob + 84410368);         // 524288
    u16*   UrzDT    = (u16*)(ob + 84934656);         // 1048576
    u16*   UnDT     = (u16*)(ob + 85983232);         // 524288
    u16*   WsT      = (u16*)(ob + 86507520);         // 524288
    u16*   WxCT     = (u16*)(ob + 87031808);         // 1572864
    u32*   hg       = (u32*)(ob + 88604672);         // 65536 (2 parities x 32KB)
    u32*   rhg      = (u32*)(ob + 88670208);         // 32768
    u32*   ctxg     = (u32*)(ob + 88702976);         // 32768
    u32*   zg       = (u32*)(ob + 88735744);         // 65536
    u32*   gg       = (u32*)(ob + 88801280);         // 65536
    u32*   aWsg     = (u32*)(ob + 88866816);         // 65536
    u32*   barp     = (u32*)(ob + 88932352);         // 4096: encFlags (32x16 u32) @0, decFlags @+2048B

    // --- d_ws: only what must coexist with the final GEMM's output ---
    char* wb = (char*)d_ws;
    u16* outWT = (u16*)(wb + 0);          // 65536000
    u16* hctx  = (u16*)(wb + 65536000);   // 8388608

    // prep: all weights -> bf16 [N][K]
    transpose_cvt<<<dim3(48, 16),   256, 0, stream>>>(enc_Wx,  encWxT, 512, 1536);
    transpose_cvt<<<dim3(48, 16),   256, 0, stream>>>(dec_Wx,  decWxET,512, 1536);
    transpose_cvt<<<dim3(16, 16),   256, 0, stream>>>(attn_Wh, WhT,    512, 512);
    transpose_cvt<<<dim3(1000, 32), 256, 0, stream>>>(out_W,   outWT, 1024, 32000);
    transpose_cvt<<<dim3(32, 16),   256, 0, stream>>>(enc_Urz, UrzET,  512, 1024);
    transpose_cvt<<<dim3(16, 16),   256, 0, stream>>>(enc_Un,  UnET,   512, 512);
    transpose_cvt<<<dim3(32, 16),   256, 0, stream>>>(dec_Urz, UrzDT,  512, 1024);
    transpose_cvt<<<dim3(16, 16),   256, 0, stream>>>(dec_Un,  UnDT,   512, 512);
    transpose_cvt<<<dim3(16, 16),   256, 0, stream>>>(attn_Ws, WsT,    512, 512);
    transpose_cvt<<<dim3(48, 16),   256, 0, stream>>>(dec_Wx + (size_t)512 * 1536, WxCT, 512, 1536);
    gather_emb_bf16<<<4096, 128, 0, stream>>>(src, enc_embed, Aenc);
    gather_emb_bf16<<<4096, 128, 0, stream>>>(tgt, dec_embed, Adec);

    // batched input-projection GEMMs
    gemm_bf16<<<dim3(12, 32), 256, 0, stream>>>(Aenc, encWxT,  enc_bx, gx_enc,  4096, 1536, 512);
    gemm_bf16<<<dim3(12, 32), 256, 0, stream>>>(Adec, decWxET, dec_bx, gxe_dec, 4096, 1536, 512);

    init_state<<<32, 512, 0, stream>>>(hg, barp);

    // encoder (persistent, 32 WGs, LDS weights)
    {
        u32* encF = barp;
        void* args[] = { (void*)&gx_enc, (void*)&UrzET, (void*)&UnET, (void*)&enc_brz,
                         (void*)&enc_bn, (void*)&hg, (void*)&rhg, (void*)&zg,
                         (void*)&enc_hs, (void*)&spack, (void*)&encF };
        hipLaunchCooperativeKernel((void*)enc_coop, dim3(32), dim3(512), args, 0, stream);
    }

    // wh_enc = enc_hs @ attn_Wh; -> bf16
    gemm_bf16<<<dim3(4, 32), 256, 0, stream>>>(enc_hs, WhT, nullptr, wh_enc, 4096, 512, 512);
    cvt_f32_bf16<<<1024, 256, 0, stream>>>(wh_enc, wh_bf);

    // decoder (persistent, 32 WGs, LDS weights; h carried in hg parity 0)
    {
        u32* decF = barp + 512;
        void* args[] = { (void*)&gxe_dec, (void*)&wh_bf, (void*)&spack, (void*)&attn_v,
                         (void*)&dec_brz, (void*)&dec_bn, (void*)&UrzDT, (void*)&WsT,
                         (void*)&WxCT, (void*)&UnDT, (void*)&hg, (void*)&rhg, (void*)&ctxg,
                         (void*)&zg, (void*)&gg, (void*)&aWsg, (void*)&hctx, (void*)&decF };
        hipLaunchCooperativeKernel((void*)dec_coop, dim3(32), dim3(512), args, 0, stream);
    }

    // output projection (overwrites ALL of d_out) + in-place log_softmax
    gemm_bf16<<<dim3(250, 32), 256, 0, stream>>>(hctx, outWT, out_b, (float*)d_out, 4096, VTOK, 1024);
    log_softmax_rows<<<4096, 256, 0, stream>>>((float*)d_out);
}

// Round 11
// 5675.024 us; speedup vs baseline: 1.1849x; 1.1849x over previous
//
#include <hip/hip_runtime.h>
#include <stdint.h>

#define BATCH 32
#define SEQ   128       // S == T == 128
#define HID   512
#define VTOK  32000

typedef unsigned short u16;
typedef unsigned int   u32;
typedef unsigned long long u64;
typedef float    f32x4  __attribute__((ext_vector_type(4)));
typedef short    short8 __attribute__((ext_vector_type(8)));

__device__ __forceinline__ u16 f2bf(float f) {
    u32 u = __builtin_bit_cast(u32, f);
    return (u16)((u + 0x7FFFu + ((u >> 16) & 1u)) >> 16);
}
__device__ __forceinline__ float bf2f(u16 v) {
    u32 u = ((u32)v) << 16; return __builtin_bit_cast(float, u);
}
__device__ __forceinline__ float fexp2(float x) { return __builtin_amdgcn_exp2f(x); }
__device__ __forceinline__ float frcp(float x)  { return __builtin_amdgcn_rcpf(x); }
__device__ __forceinline__ float sigmoid_f(float x) {
    return frcp(1.f + fexp2(-1.442695040888963f * x));
}
__device__ __forceinline__ float tanh_f(float x) {
    return 1.f - 2.f * frcp(1.f + fexp2(2.885390081777927f * x));
}

// ---- LLC-coherent (sc1) relaxed atomics (flags / scalar comm) ----
__device__ __forceinline__ u32 ld_sc1_u32(const u32* p) {
    return __hip_atomic_load(p, __ATOMIC_RELAXED, __HIP_MEMORY_SCOPE_AGENT);
}
__device__ __forceinline__ void st_sc1_u32(u32* p, u32 v) {
    __hip_atomic_store(p, v, __ATOMIC_RELAXED, __HIP_MEMORY_SCOPE_AGENT);
}

// ---- BATCHED coherent loads: issue many sc1 loads back-to-back (pipelined),
// then one s_waitcnt + sched_barrier. Same cache-bypass bits as the relaxed
// agent atomic load, but WITHOUT LLVM's conservative atomic ordering (which
// serialized the k-loop at one LLC round-trip per load — the ~8 us/phase wall).
__device__ __forceinline__ void ld16_async(uint4& dst, const void* p) {
    asm volatile("global_load_dwordx4 %0, %1, off sc1" : "=v"(dst) : "v"(p));
}
__device__ __forceinline__ void ld4_async(u32& dst, const void* p) {
    asm volatile("global_load_dword %0, %1, off sc1" : "=v"(dst) : "v"(p));
}
__device__ __forceinline__ void wait_vm0() {
    asm volatile("s_waitcnt vmcnt(0)" ::: "memory");
    __builtin_amdgcn_sched_barrier(0);   // rule #18: stop MFMA hoisting past the wait
}

// ---- symmetric all-report/all-poll barrier over 32 WGs ----
__device__ __forceinline__ void gbar32(u32* flags, u32 gen) {
    asm volatile("s_waitcnt vmcnt(0)" ::: "memory");
    __syncthreads();
    if (threadIdx.x == 0) st_sc1_u32(flags + (u32)blockIdx.x * 16, gen);
    const int i = threadIdx.x;
    if (i < 32 && i != (int)blockIdx.x) {
        while (ld_sc1_u32(flags + i * 16) < gen) {}
    }
    __syncthreads();
}

// ---------------- prep kernels ----------------

__global__ __launch_bounds__(256) void transpose_cvt(
    const float* __restrict__ src, u16* __restrict__ dst, int K, int N)
{
    __shared__ float tile[32][33];
    const int n0 = blockIdx.x * 32, k0 = blockIdx.y * 32;
    const int tx = threadIdx.x & 31, ty = threadIdx.x >> 5;
    #pragma unroll
    for (int j = 0; j < 32; j += 8)
        tile[ty + j][tx] = src[(size_t)(k0 + ty + j) * N + n0 + tx];
    __syncthreads();
    #pragma unroll
    for (int j = 0; j < 32; j += 8)
        dst[(size_t)(n0 + ty + j) * K + k0 + tx] = f2bf(tile[tx][ty + j]);
}

__global__ __launch_bounds__(256) void cvt_f32_bf16(
    const float* __restrict__ src, u16* __restrict__ dst)
{
    const size_t i = ((size_t)blockIdx.x * 256 + threadIdx.x) * 8;
    float4 v0 = *(const float4*)(src + i);
    float4 v1 = *(const float4*)(src + i + 4);
    uint4 pk;
    pk.x = (u32)f2bf(v0.x) | ((u32)f2bf(v0.y) << 16);
    pk.y = (u32)f2bf(v0.z) | ((u32)f2bf(v0.w) << 16);
    pk.z = (u32)f2bf(v1.x) | ((u32)f2bf(v1.y) << 16);
    pk.w = (u32)f2bf(v1.z) | ((u32)f2bf(v1.w) << 16);
    *(uint4*)(dst + i) = pk;
}

__global__ __launch_bounds__(128) void gather_emb_bf16(
    const int* __restrict__ idx, const float* __restrict__ emb, u16* __restrict__ out)
{
    const int r = blockIdx.x;
    const int token = idx[r];
    const int i = threadIdx.x * 4;
    float4 v = *(const float4*)(emb + (size_t)token * 512 + i);
    uint2 pk;
    pk.x = (u32)f2bf(v.x) | ((u32)f2bf(v.y) << 16);
    pk.y = (u32)f2bf(v.z) | ((u32)f2bf(v.w) << 16);
    *(uint2*)(out + (size_t)r * 512 + i) = pk;
}

__global__ __launch_bounds__(512) void init_state(u32* hg, u32* bar)
{
    const int i = blockIdx.x * 512 + threadIdx.x;
    hg[i] = 0u;
    if (blockIdx.x < 2) bar[blockIdx.x * 512 + threadIdx.x] = 0u;
}

// ---------------- MFMA GEMM:  C[M,N](f32) = A[M,K](bf16) * BT[N,K](bf16) + bias ----------------
__global__ __launch_bounds__(256) void gemm_bf16(
    const u16* __restrict__ A, const u16* __restrict__ BT,
    const float* __restrict__ bias, float* __restrict__ C,
    int M, int N, int K)
{
    __shared__ __align__(16) u16 As[128][40];
    __shared__ __align__(16) u16 Bs[128][40];
    const int tid  = threadIdx.x;
    const int lane = tid & 63, wave = tid >> 6;
    const int wm = (wave & 1) * 64, wn = (wave >> 1) * 64;
    const int lrow = lane & 15, lk = (lane >> 4) * 8;
    const int srow = tid >> 2, skof = (tid & 3) * 8;
    const size_t K_ = (size_t)K;
    const u16* Ag = A + ((size_t)blockIdx.y * 128 + srow) * K_ + skof;
    const u16* Bg = BT + ((size_t)blockIdx.x * 128 + srow) * K_ + skof;
    f32x4 acc[4][4] = {};
    for (int k0 = 0; k0 < K; k0 += 32) {
        uint4 a0 = *(const uint4*)(Ag + k0);
        uint4 a1 = *(const uint4*)(Ag + 64 * K_ + k0);
        uint4 b0 = *(const uint4*)(Bg + k0);
        uint4 b1 = *(const uint4*)(Bg + 64 * K_ + k0);
        __syncthreads();
        *(uint4*)&As[srow][skof]      = a0;
        *(uint4*)&As[srow + 64][skof] = a1;
        *(uint4*)&Bs[srow][skof]      = b0;
        *(uint4*)&Bs[srow + 64][skof] = b1;
        __syncthreads();
        short8 af[4], bf[4];
        #pragma unroll
        for (int i = 0; i < 4; ++i) af[i] = *(const short8*)&As[wm + i * 16 + lrow][lk];
        #pragma unroll
        for (int j = 0; j < 4; ++j) bf[j] = *(const short8*)&Bs[wn + j * 16 + lrow][lk];
        #pragma unroll
        for (int i = 0; i < 4; ++i)
            #pragma unroll
            for (int j = 0; j < 4; ++j)
                acc[i][j] = __builtin_amdgcn_mfma_f32_16x16x32_bf16(af[i], bf[j], acc[i][j], 0, 0, 0);
    }
    const int crow0 = blockIdx.y * 128 + wm + (lane >> 4) * 4;
    const int ccol0 = blockIdx.x * 128 + wn + (lane & 15);
    #pragma unroll
    for (int j = 0; j < 4; ++j) {
        const float bv = bias ? bias[ccol0 + j * 16] : 0.f;
        #pragma unroll
        for (int i = 0; i < 4; ++i)
            #pragma unroll
            for (int rr = 0; rr < 4; ++rr)
                C[(size_t)(crow0 + i * 16 + rr) * N + (ccol0 + j * 16)] = acc[i][j][rr] + bv;
    }
}

// ============ persistent encoder: 32 WGs, LDS weights, batched coherent loads ============
__global__ __launch_bounds__(512) void enc_coop(
    const float* __restrict__ gx, const u16* __restrict__ Urz, const u16* __restrict__ Un,
    const float* __restrict__ brz, const float* __restrict__ bn,
    u32* __restrict__ hg, u32* __restrict__ rhg, u32* __restrict__ zg,
    u16* __restrict__ enc_hs, u16* __restrict__ spack,
    u32* __restrict__ flags)
{
    const int w = blockIdx.x, tid = threadIdx.x;
    const int v = tid >> 6, lane = tid & 63;
    const int nl = lane & 15, kq = lane >> 4;
    __shared__ __align__(16) u16 UrzS[32][520];
    __shared__ __align__(16) u16 UnS[16][520];
    for (int idx = tid; idx < 32 * 64; idx += 512) {
        const int r = idx >> 6, c = idx & 63;
        *(uint4*)&UrzS[r][c * 8] = *(const uint4*)(Urz + (size_t)(w * 32 + r) * 512 + c * 8);
    }
    for (int idx = tid; idx < 16 * 64; idx += 512) {
        const int r = idx >> 6, c = idx & 63;
        *(uint4*)&UnS[r][c * 8] = *(const uint4*)(Un + (size_t)(w * 16 + r) * 512 + c * 8);
    }
    __syncthreads();
    for (int t = 0; t < SEQ; ++t) {
        const u32* hgA = hg + (t & 1) * 8192;
        u32*       hgW = hg + ((t + 1) & 1) * 8192;
        const u64* hq  = (const u64*)hgA;
        const u64* rq  = (const u64*)rhg;
        // ---- E1: h@Urz (waves 0..3) ----
        if (v < 4) {
            const int bt = v & 1, tl = v >> 1;
            const int n = w * 32 + tl * 16 + nl;
            const int brow = bt * 16 + nl;
            uint4 a[16]; u32 hvp[4];
            const u64* ab = hq + brow * 128 + kq * 2;
            #pragma unroll
            for (int i = 0; i < 16; ++i) ld16_async(a[i], ab + i * 8);
            #pragma unroll
            for (int rr = 0; rr < 4; ++rr)
                ld4_async(hvp[rr], hgA + (bt * 16 + kq * 4 + rr) * 256 + (n >> 1));
            float gxr_pf[4];
            #pragma unroll
            for (int rr = 0; rr < 4; ++rr) {
                const int b = bt * 16 + kq * 4 + rr;
                gxr_pf[rr] = gx[((size_t)(b * SEQ + t)) * 1536 + n];
            }
            wait_vm0();
            const u16* wl = &UrzS[tl * 16 + nl][0];
            f32x4 acc = {0.f, 0.f, 0.f, 0.f};
            #pragma unroll
            for (int i = 0; i < 16; ++i) {
                short8 bfv = *(const short8*)(wl + i * 32 + kq * 8);
                acc = __builtin_amdgcn_mfma_f32_16x16x32_bf16(
                    __builtin_bit_cast(short8, a[i]), bfv, acc, 0, 0, 0);
            }
            if (n < 512) {               // r gate -> rh
                u32 pk[4];
                #pragma unroll
                for (int rr = 0; rr < 4; ++rr) {
                    const float r = sigmoid_f(gxr_pf[rr] + acc[rr] + brz[n]);
                    const float hold = bf2f((u16)((n & 1) ? (hvp[rr] >> 16) : (hvp[rr] & 0xFFFF)));
                    pk[rr] = (u32)f2bf(r * hold);
                }
                #pragma unroll
                for (int rr = 0; rr < 4; ++rr) {
                    u32 oth = (u32)__shfl_xor((int)pk[rr], 1);
                    if ((n & 1) == 0) {
                        const int b = bt * 16 + kq * 4 + rr;
                        st_sc1_u32(rhg + b * 256 + (n >> 1), (pk[rr] & 0xFFFF) | (oth << 16));
                    }
                }
            } else {                     // z gate
                #pragma unroll
                for (int rr = 0; rr < 4; ++rr) {
                    const int b = bt * 16 + kq * 4 + rr;
                    const float z = sigmoid_f(gxr_pf[rr] + acc[rr] + brz[n]);
                    st_sc1_u32(zg + (n - 512) * 32 + b, __float_as_uint(z));
                }
            }
        }
        gbar32(flags, (u32)(2 * t + 1));
        // ---- E2: (r*h)@Un, h update (waves 0..1) ----
        if (v < 2) {
            const int bt = v;
            const int n = w * 16 + nl;
            const int brow = bt * 16 + nl;
            uint4 a[16]; u32 hvp[4], zvp[4];
            const u64* ab = rq + brow * 128 + kq * 2;
            #pragma unroll
            for (int i = 0; i < 16; ++i) ld16_async(a[i], ab + i * 8);
            #pragma unroll
            for (int rr = 0; rr < 4; ++rr) {
                const int b = bt * 16 + kq * 4 + rr;
                ld4_async(hvp[rr], hgA + b * 256 + (n >> 1));
                ld4_async(zvp[rr], zg + n * 32 + b);
            }
            float gxr_pf[4];
            #pragma unroll
            for (int rr = 0; rr < 4; ++rr) {
                const int b = bt * 16 + kq * 4 + rr;
                gxr_pf[rr] = gx[((size_t)(b * SEQ + t)) * 1536 + 1024 + n];
            }
            wait_vm0();
            const u16* wl = &UnS[nl][0];
            f32x4 acc = {0.f, 0.f, 0.f, 0.f};
            #pragma unroll
            for (int i = 0; i < 16; ++i) {
                short8 bfv = *(const short8*)(wl + i * 32 + kq * 8);
                acc = __builtin_amdgcn_mfma_f32_16x16x32_bf16(
                    __builtin_bit_cast(short8, a[i]), bfv, acc, 0, 0, 0);
            }
            u32 pk[4];
            #pragma unroll
            for (int rr = 0; rr < 4; ++rr) {
                const int b = bt * 16 + kq * 4 + rr;
                const float nn = tanh_f(gxr_pf[rr] + acc[rr] + bn[n]);
                const float z = __uint_as_float(zvp[rr]);
                const float hold = bf2f((u16)((n & 1) ? (hvp[rr] >> 16) : (hvp[rr] & 0xFFFF)));
                const float hn = (1.f - z) * hold + z * nn;
                const u16 hb = f2bf(hn);
                pk[rr] = (u32)hb;
                enc_hs[((size_t)(b * SEQ + t)) * 512 + n] = hb;
                spack[(((size_t)b * 16 + (t >> 3)) * 512 + n) * 8 + (t & 7)] = hb;
            }
            #pragma unroll
            for (int rr = 0; rr < 4; ++rr) {
                u32 oth = (u32)__shfl_xor((int)pk[rr], 1);
                if ((n & 1) == 0) {
                    const int b = bt * 16 + kq * 4 + rr;
                    st_sc1_u32(hgW + b * 256 + (n >> 1), (pk[rr] & 0xFFFF) | (oth << 16));
                }
            }
        }
        gbar32(flags, (u32)(2 * t + 2));
    }
}

// ============ persistent decoder: 32 WGs, LDS weights, batched coherent loads ============
__global__ __launch_bounds__(512) void dec_coop(
    const float* __restrict__ gxe, const u16* __restrict__ wh_bf, const u16* __restrict__ spack,
    const float* __restrict__ attn_v, const float* __restrict__ brz, const float* __restrict__ bn,
    const u16* __restrict__ Urz, const u16* __restrict__ Ws,
    const u16* __restrict__ WxC, const u16* __restrict__ Un,
    u32* __restrict__ hg, u32* __restrict__ rhg, u32* __restrict__ ctxg,
    u32* __restrict__ zg, u32* __restrict__ gg, u32* __restrict__ aWsg,
    u16* __restrict__ hctx, u32* __restrict__ flags)
{
    const int w = blockIdx.x, tid = threadIdx.x;
    const int v = tid >> 6, lane = tid & 63;
    const int nl = lane & 15, kq = lane >> 4;
    __shared__ __align__(16) u16 UWsS[48][520];
    __shared__ __align__(16) u16 WxCS[48][520];
    __shared__ __align__(16) u16 UnS2[16][520];
    __shared__ float hWsL[4 * 132], redE[512], attnL[128];
    __shared__ u16 ctxL[512];
    for (int idx = tid; idx < 48 * 64; idx += 512) {
        const int r = idx >> 6, c = idx & 63;
        const int gcol = w * 48 + r;
        const u16* s0 = (gcol < 1024 ? Urz + (size_t)gcol * 512
                                     : Ws + (size_t)(gcol - 1024) * 512) + c * 8;
        *(uint4*)&UWsS[r][c * 8] = *(const uint4*)s0;
        *(uint4*)&WxCS[r][c * 8] = *(const uint4*)(WxC + (size_t)gcol * 512 + c * 8);
    }
    for (int idx = tid; idx < 16 * 64; idx += 512) {
        const int r = idx >> 6, c = idx & 63;
        *(uint4*)&UnS2[r][c * 8] = *(const uint4*)(Un + (size_t)(w * 16 + r) * 512 + c * 8);
    }
    __syncthreads();
    for (int t = 0; t < SEQ; ++t) {
        const u32* hgA = hg + (t & 1) * 8192;
        u32*       hgW = hg + ((t + 1) & 1) * 8192;
        const u64* hq  = (const u64*)hgA;
        const u64* rq  = (const u64*)rhg;
        const u64* cq  = (const u64*)ctxg;
        f32x4 aPk = {0.f, 0.f, 0.f, 0.f};
        // ---- P1: h@[Urz | Ws] (waves 0..5) ----
        if (v < 6) {
            const int bt = v & 1, tl = v >> 1;
            const int n = w * 48 + tl * 16 + nl;
            const int brow = bt * 16 + nl;
            uint4 a[16];
            const u64* ab = hq + brow * 128 + kq * 2;
            #pragma unroll
            for (int i = 0; i < 16; ++i) ld16_async(a[i], ab + i * 8);
            wait_vm0();
            const u16* wl = &UWsS[tl * 16 + nl][0];
            f32x4 acc = {0.f, 0.f, 0.f, 0.f};
            #pragma unroll
            for (int i = 0; i < 16; ++i) {
                short8 bfv = *(const short8*)(wl + i * 32 + kq * 8);
                acc = __builtin_amdgcn_mfma_f32_16x16x32_bf16(
                    __builtin_bit_cast(short8, a[i]), bfv, acc, 0, 0, 0);
            }
            if (n < 1024) {
                aPk = acc;               // persists in regs to P3
            } else {
                #pragma unroll
                for (int rr = 0; rr < 4; ++rr) {
                    const int b = bt * 16 + kq * 4 + rr;
                    st_sc1_u32(aWsg + (n - 1024) * 32 + b, __float_as_uint(acc[rr]));
                }
            }
        }
        gbar32(flags, (u32)(4 * t + 1));
        // ---- P2: attention (all 32 WGs, b = w) ----
        {
            const int b = w;
            {
                u32 hwv;
                ld4_async(hwv, aWsg + tid * 32 + b);
                wait_vm0();
                hWsL[(tid >> 7) * 132 + (tid & 127)] = __uint_as_float(hwv);
            }
            __syncthreads();
            {
                const int s = tid >> 2, q = tid & 3;
                const u16* whr = wh_bf + ((size_t)(b * SEQ + s)) * 512 + q * 128;
                const float* avq = attn_v + q * 128;
                const float* hwq = &hWsL[q * 132];
                float e = 0.f;
                #pragma unroll 4
                for (int i = 0; i < 128; i += 8) {
                    uint4 wv = *(const uint4*)(whr + i);
                    float4 h0 = *(const float4*)(hwq + i);
                    float4 h1 = *(const float4*)(hwq + i + 4);
                    float4 v0 = *(const float4*)(avq + i);
                    float4 v1 = *(const float4*)(avq + i + 4);
                    e += v0.x * tanh_f(bf2f((u16)(wv.x & 0xFFFF)) + h0.x)
                       + v0.y * tanh_f(bf2f((u16)(wv.x >> 16))    + h0.y)
                       + v0.z * tanh_f(bf2f((u16)(wv.y & 0xFFFF)) + h0.z)
                       + v0.w * tanh_f(bf2f((u16)(wv.y >> 16))    + h0.w)
                       + v1.x * tanh_f(bf2f((u16)(wv.z & 0xFFFF)) + h1.x)
                       + v1.y * tanh_f(bf2f((u16)(wv.z >> 16))    + h1.y)
                       + v1.z * tanh_f(bf2f((u16)(wv.w & 0xFFFF)) + h1.z)
                       + v1.w * tanh_f(bf2f((u16)(wv.w >> 16))    + h1.w);
                }
                redE[tid] = e;
            }
            __syncthreads();
            if (tid < 64) {
                float e0 = redE[4 * tid] + redE[4 * tid + 1] + redE[4 * tid + 2] + redE[4 * tid + 3];
                float e1 = redE[4 * (tid + 64)] + redE[4 * (tid + 64) + 1]
                         + redE[4 * (tid + 64) + 2] + redE[4 * (tid + 64) + 3];
                float m = fmaxf(e0, e1);
                for (int o = 32; o >= 1; o >>= 1) m = fmaxf(m, __shfl_xor(m, o));
                float p0 = fexp2((e0 - m) * 1.442695040888963f);
                float p1 = fexp2((e1 - m) * 1.442695040888963f);
                float ss = p0 + p1;
                for (int o = 32; o >= 1; o >>= 1) ss += __shfl_xor(ss, o);
                const float inv = frcp(ss);
                attnL[tid]      = p0 * inv;
                attnL[tid + 64] = p1 * inv;
            }
            __syncthreads();
            {
                const int d = tid;
                float cv = 0.f;
                const u16* sp = spack + ((size_t)b * 16 * 512 + d) * 8;
                #pragma unroll 4
                for (int sb = 0; sb < 16; ++sb) {
                    uint4 sv = *(const uint4*)(sp + (size_t)sb * 4096);
                    const float* al = &attnL[sb * 8];
                    cv += al[0] * bf2f((u16)(sv.x & 0xFFFF)) + al[1] * bf2f((u16)(sv.x >> 16))
                        + al[2] * bf2f((u16)(sv.y & 0xFFFF)) + al[3] * bf2f((u16)(sv.y >> 16))
                        + al[4] * bf2f((u16)(sv.z & 0xFFFF)) + al[5] * bf2f((u16)(sv.z >> 16))
                        + al[6] * bf2f((u16)(sv.w & 0xFFFF)) + al[7] * bf2f((u16)(sv.w >> 16));
                }
                const u16 cb = f2bf(cv);
                ctxL[d] = cb;
                hctx[((size_t)(b * SEQ + t)) * 1024 + 512 + d] = cb;
            }
            __syncthreads();
            if (tid < 256) {
                u32 pk = (u32)ctxL[2 * tid] | ((u32)ctxL[2 * tid + 1] << 16);
                st_sc1_u32(ctxg + b * 256 + tid, pk);
            }
        }
        gbar32(flags, (u32)(4 * t + 2));
        // ---- P3: ctx@WxC + gates (waves 0..5; aPk from P1) ----
        if (v < 6) {
            const int bt = v & 1, tl = v >> 1;
            const int n = w * 48 + tl * 16 + nl;
            const int brow = bt * 16 + nl;
            uint4 a[16]; u32 hvp[4];
            const u64* ab = cq + brow * 128 + kq * 2;
            #pragma unroll
            for (int i = 0; i < 16; ++i) ld16_async(a[i], ab + i * 8);
            #pragma unroll
            for (int rr = 0; rr < 4; ++rr)
                ld4_async(hvp[rr], hgA + (bt * 16 + kq * 4 + rr) * 256 + ((n & 511) >> 1));
            float gxr_pf[4];
            #pragma unroll
            for (int rr = 0; rr < 4; ++rr) {
                const int b = bt * 16 + kq * 4 + rr;
                gxr_pf[rr] = gxe[((size_t)(b * SEQ + t)) * 1536 + n];
            }
            wait_vm0();
            const u16* wl = &WxCS[tl * 16 + nl][0];
            f32x4 acc = {0.f, 0.f, 0.f, 0.f};
            #pragma unroll
            for (int i = 0; i < 16; ++i) {
                short8 bfv = *(const short8*)(wl + i * 32 + kq * 8);
                acc = __builtin_amdgcn_mfma_f32_16x16x32_bf16(
                    __builtin_bit_cast(short8, a[i]), bfv, acc, 0, 0, 0);
            }
            if (n < 512) {               // r gate -> rh
                u32 pk[4];
                #pragma unroll
                for (int rr = 0; rr < 4; ++rr) {
                    const float r = sigmoid_f(gxr_pf[rr] + acc[rr] + aPk[rr] + brz[n]);
                    const float hold = bf2f((u16)((n & 1) ? (hvp[rr] >> 16) : (hvp[rr] & 0xFFFF)));
                    pk[rr] = (u32)f2bf(r * hold);
                }
                #pragma unroll
                for (int rr = 0; rr < 4; ++rr) {
                    u32 oth = (u32)__shfl_xor((int)pk[rr], 1);
                    if ((n & 1) == 0) {
                        const int b = bt * 16 + kq * 4 + rr;
                        st_sc1_u32(rhg + b * 256 + (n >> 1), (pk[rr] & 0xFFFF) | (oth << 16));
                    }
                }
            } else if (n < 1024) {       // z gate
                #pragma unroll
                for (int rr = 0; rr < 4; ++rr) {
                    const int b = bt * 16 + kq * 4 + rr;
                    const float z = sigmoid_f(gxr_pf[rr] + acc[rr] + aPk[rr] + brz[n]);
                    st_sc1_u32(zg + (n - 512) * 32 + b, __float_as_uint(z));
                }
            } else {                     // n-gate pre-activation
                #pragma unroll
                for (int rr = 0; rr < 4; ++rr) {
                    const int b = bt * 16 + kq * 4 + rr;
                    st_sc1_u32(gg + (n - 1024) * 32 + b, __float_as_uint(gxr_pf[rr] + acc[rr]));
                }
            }
        }
        gbar32(flags, (u32)(4 * t + 3));
        // ---- P4: (r*h)@Un, h update (waves 0..1) ----
        if (v < 2) {
            const int bt = v;
            const int n = w * 16 + nl;
            const int brow = bt * 16 + nl;
            uint4 a[16]; u32 gvp[4], zvp[4], hvp[4];
            const u64* ab = rq + brow * 128 + kq * 2;
            #pragma unroll
            for (int i = 0; i < 16; ++i) ld16_async(a[i], ab + i * 8);
            #pragma unroll
            for (int rr = 0; rr < 4; ++rr) {
                const int b = bt * 16 + kq * 4 + rr;
                ld4_async(gvp[rr], gg + n * 32 + b);
                ld4_async(zvp[rr], zg + n * 32 + b);
                ld4_async(hvp[rr], hgA + b * 256 + (n >> 1));
            }
            wait_vm0();
            const u16* wl = &UnS2[nl][0];
            f32x4 acc = {0.f, 0.f, 0.f, 0.f};
            #pragma unroll
            for (int i = 0; i < 16; ++i) {
                short8 bfv = *(const short8*)(wl + i * 32 + kq * 8);
                acc = __builtin_amdgcn_mfma_f32_16x16x32_bf16(
                    __builtin_bit_cast(short8, a[i]), bfv, acc, 0, 0, 0);
            }
            u32 pk[4];
            #pragma unroll
            for (int rr = 0; rr < 4; ++rr) {
                const int b = bt * 16 + kq * 4 + rr;
                const float nn = tanh_f(__uint_as_float(gvp[rr]) + acc[rr] + bn[n]);
                const float z = __uint_as_float(zvp[rr]);
                const float hold = bf2f((u16)((n & 1) ? (hvp[rr] >> 16) : (hvp[rr] & 0xFFFF)));
                const float hn = (1.f - z) * hold + z * nn;
                const u16 hb = f2bf(hn);
                pk[rr] = (u32)hb;
                hctx[((size_t)(b * SEQ + t)) * 1024 + n] = hb;
            }
            #pragma unroll
            for (int rr = 0; rr < 4; ++rr) {
                u32 oth = (u32)__shfl_xor((int)pk[rr], 1);
                if ((n & 1) == 0) {
                    const int b = bt * 16 + kq * 4 + rr;
                    st_sc1_u32(hgW + b * 256 + (n >> 1), (pk[rr] & 0xFFFF) | (oth << 16));
                }
            }
        }
        gbar32(flags, (u32)(4 * t + 4));
    }
}

// ---------------- log_softmax: 2-pass (online max+sum), in-place on [4096, 32000] ----------------
__global__ __launch_bounds__(256) void log_softmax_rows(float* __restrict__ out)
{
    const int row = blockIdx.x, tid = threadIdx.x;
    float* p = out + (size_t)row * VTOK;
    __shared__ float rbM[4], rbS[4];
    const float L2E = 1.442695040888963f;
    float m = -3.0e38f, s = 0.f;
    for (int i = tid * 4; i < VTOK; i += 1024) {
        float4 v = *(const float4*)(p + i);
        float lm = fmaxf(fmaxf(v.x, v.y), fmaxf(v.z, v.w));
        float nm = fmaxf(m, lm);
        s = s * fexp2((m - nm) * L2E)
          + fexp2((v.x - nm) * L2E) + fexp2((v.y - nm) * L2E)
          + fexp2((v.z - nm) * L2E) + fexp2((v.w - nm) * L2E);
        m = nm;
    }
    for (int o = 32; o >= 1; o >>= 1) {
        float om = __shfl_xor(m, o), os = __shfl_xor(s, o);
        float nm = fmaxf(m, om);
        s = s * fexp2((m - nm) * L2E) + os * fexp2((om - nm) * L2E);
        m = nm;
    }
    if ((tid & 63) == 0) { rbM[tid >> 6] = m; rbS[tid >> 6] = s; }
    __syncthreads();
    {
        float fm = fmaxf(fmaxf(rbM[0], rbM[1]), fmaxf(rbM[2], rbM[3]));
        float fs = rbS[0] * fexp2((rbM[0] - fm) * L2E) + rbS[1] * fexp2((rbM[1] - fm) * L2E)
                 + rbS[2] * fexp2((rbM[2] - fm) * L2E) + rbS[3] * fexp2((rbM[3] - fm) * L2E);
        m = fm; s = fs;
    }
    const float lse = m + __builtin_amdgcn_logf(s) * 0.6931471805599453f;
    for (int i = tid * 4; i < VTOK; i += 1024) {
        float4 v = *(const float4*)(p + i);
        v.x -= lse; v.y -= lse; v.z -= lse; v.w -= lse;
        *(float4*)(p + i) = v;
    }
}

// ---------------- host launcher ----------------
extern "C" void kernel_launch(void* const* d_in, const int* in_sizes, int n_in,
                              void* d_out, int out_size, void* d_ws, size_t ws_size,
                              hipStream_t stream)
{
    (void)in_sizes; (void)n_in; (void)out_size; (void)ws_size;
    const int*   src       = (const int*)  d_in[0];
    const int*   tgt       = (const int*)  d_in[1];
    const float* enc_embed = (const float*)d_in[2];
    const float* enc_Wx    = (const float*)d_in[3];
    const float* enc_bx    = (const float*)d_in[4];
    const float* enc_Urz   = (const float*)d_in[5];
    const float* enc_brz   = (const float*)d_in[6];
    const float* enc_Un    = (const float*)d_in[7];
    const float* enc_bn    = (const float*)d_in[8];
    const float* dec_embed = (const float*)d_in[9];
    const float* dec_Wx    = (const float*)d_in[10];
    const float* dec_bx    = (const float*)d_in[11];
    const float* dec_Urz   = (const float*)d_in[12];
    const float* dec_brz   = (const float*)d_in[13];
    const float* dec_Un    = (const float*)d_in[14];
    const float* dec_bn    = (const float*)d_in[15];
    const float* attn_Wh   = (const float*)d_in[16];
    const float* attn_Ws   = (const float*)d_in[17];
    const float* attn_v    = (const float*)d_in[18];
    const float* out_W     = (const float*)d_in[19];
    const float* out_b     = (const float*)d_in[20];

    // --- scratch in d_out (524,288,000 B); all dead before the final GEMM overwrites ---
    char* ob = (char*)d_out;
    float* gx_enc   = (float*)(ob + 0);
    float* gxe_dec  = (float*)(ob + 25165824);
    float* wh_enc   = (float*)(ob + 50331648);
    u16*   Aenc     = (u16*)(ob + 58720256);
    u16*   Adec     = (u16*)(ob + 62914560);
    u16*   enc_hs   = (u16*)(ob + 67108864);
    u16*   spack    = (u16*)(ob + 71303168);
    u16*   wh_bf    = (u16*)(ob + 75497472);
    u16*   encWxT   = (u16*)(ob + 79691776);
    u16*   decWxET  = (u16*)(ob + 81264640);
    u16*   WhT      = (u16*)(ob + 82837504);
    u16*   UrzET    = (u16*)(ob + 83361792);
    u16*   UnET     = (u16*)(ob + 84410368);
    u16*   UrzDT    = (u16*)(ob + 84934656);
    u16*   UnDT     = (u16*)(ob + 85983232);
    u16*   WsT      = (u16*)(ob + 86507520);
    u16*   WxCT     = (u16*)(ob + 87031808);
    u32*   hg       = (u32*)(ob + 88604672);
    u32*   rhg      = (u32*)(ob + 88670208);
    u32*   ctxg     = (u32*)(ob + 88702976);
    u32*   zg       = (u32*)(ob + 88735744);
    u32*   gg       = (u32*)(ob + 88801280);
    u32*   aWsg     = (u32*)(ob + 88866816);
    u32*   barp     = (u32*)(ob + 88932352);

    // --- d_ws: only what must coexist with the final GEMM's output ---
    char* wb = (char*)d_ws;
    u16* outWT = (u16*)(wb + 0);
    u16* hctx  = (u16*)(wb + 65536000);

    transpose_cvt<<<dim3(48, 16),   256, 0, stream>>>(enc_Wx,  encWxT, 512, 1536);
    transpose_cvt<<<dim3(48, 16),   256, 0, stream>>>(dec_Wx,  decWxET,512, 1536);
    transpose_cvt<<<dim3(16, 16),   256, 0, stream>>>(attn_Wh, WhT,    512, 512);
    transpose_cvt<<<dim3(1000, 32), 256, 0, stream>>>(out_W,   outWT, 1024, 32000);
    transpose_cvt<<<dim3(32, 16),   256, 0, stream>>>(enc_Urz, UrzET,  512, 1024);
    transpose_cvt<<<dim3(16, 16),   256, 0, stream>>>(enc_Un,  UnET,   512, 512);
    transpose_cvt<<<dim3(32, 16),   256, 0, stream>>>(dec_Urz, UrzDT,  512, 1024);
    transpose_cvt<<<dim3(16, 16),   256, 0, stream>>>(dec_Un,  UnDT,   512, 512);
    transpose_cvt<<<dim3(16, 16),   256, 0, stream>>>(attn_Ws, WsT,    512, 512);
    transpose_cvt<<<dim3(48, 16),   256, 0, stream>>>(dec_Wx + (size_t)512 * 1536, WxCT, 512, 1536);
    gather_emb_bf16<<<4096, 128, 0, stream>>>(src, enc_embed, Aenc);
    gather_emb_bf16<<<4096, 128, 0, stream>>>(tgt, dec_embed, Adec);

    gemm_bf16<<<dim3(12, 32), 256, 0, stream>>>(Aenc, encWxT,  enc_bx, gx_enc,  4096, 1536, 512);
    gemm_bf16<<<dim3(12, 32), 256, 0, stream>>>(Adec, decWxET, dec_bx, gxe_dec, 4096, 1536, 512);

    init_state<<<32, 512, 0, stream>>>(hg, barp);

    // encoder (persistent, 32 WGs, LDS weights)
    {
        u32* encF = barp;
        void* args[] = { (void*)&gx_enc, (void*)&UrzET, (void*)&UnET, (void*)&enc_brz,
                         (void*)&enc_bn, (void*)&hg, (void*)&rhg, (void*)&zg,
                         (void*)&enc_hs, (void*)&spack, (void*)&encF };
        hipLaunchCooperativeKernel((void*)enc_coop, dim3(32), dim3(512), args, 0, stream);
    }

    gemm_bf16<<<dim3(4, 32), 256, 0, stream>>>(enc_hs, WhT, nullptr, wh_enc, 4096, 512, 512);
    cvt_f32_bf16<<<1024, 256, 0, stream>>>(wh_enc, wh_bf);

    // decoder (persistent, 32 WGs, LDS weights; h carried in hg parity 0)
    {
        u32* decF = barp + 512;
        void* args[] = { (void*)&gxe_dec, (void*)&wh_bf, (void*)&spack, (void*)&attn_v,
                         (void*)&dec_brz, (void*)&dec_bn, (void*)&UrzDT, (void*)&WsT,
                         (void*)&WxCT, (void*)&UnDT, (void*)&hg, (void*)&rhg, (void*)&ctxg,
                         (void*)&zg, (void*)&gg, (void*)&aWsg, (void*)&hctx, (void*)&decF };
        hipLaunchCooperativeKernel((void*)dec_coop, dim3(32), dim3(512), args, 0, stream);
    }

    gemm_bf16<<<dim3(250, 32), 256, 0, stream>>>(hctx, outWT, out_b, (float*)d_out, 4096, VTOK, 1024);
    log_softmax_rows<<<4096, 256, 0, stream>>>((float*)d_out);
}

// Round 12
// 5436.837 us; speedup vs baseline: 1.2368x; 1.0438x over previous
//
#include <hip/hip_runtime.h>
#include <stdint.h>

#define BATCH 32
#define SEQ   128       // S == T == 128
#define HID   512
#define VTOK  32000

typedef unsigned short u16;
typedef unsigned int   u32;
typedef unsigned long long u64;
typedef float    f32x4  __attribute__((ext_vector_type(4)));
typedef short    short8 __attribute__((ext_vector_type(8)));

__device__ __forceinline__ u16 f2bf(float f) {
    u32 u = __builtin_bit_cast(u32, f);
    return (u16)((u + 0x7FFFu + ((u >> 16) & 1u)) >> 16);
}
__device__ __forceinline__ float bf2f(u16 v) {
    u32 u = ((u32)v) << 16; return __builtin_bit_cast(float, u);
}
__device__ __forceinline__ float fexp2(float x) { return __builtin_amdgcn_exp2f(x); }
__device__ __forceinline__ float frcp(float x)  { return __builtin_amdgcn_rcpf(x); }
__device__ __forceinline__ float sigmoid_f(float x) {
    return frcp(1.f + fexp2(-1.442695040888963f * x));
}
__device__ __forceinline__ float tanh_f(float x) {
    return 1.f - 2.f * frcp(1.f + fexp2(2.885390081777927f * x));
}

// ---- LLC-coherent (sc1) relaxed atomics (flags / scalar comm) ----
__device__ __forceinline__ u32 ld_sc1_u32(const u32* p) {
    return __hip_atomic_load(p, __ATOMIC_RELAXED, __HIP_MEMORY_SCOPE_AGENT);
}
__device__ __forceinline__ void st_sc1_u32(u32* p, u32 v) {
    __hip_atomic_store(p, v, __ATOMIC_RELAXED, __HIP_MEMORY_SCOPE_AGENT);
}

// ---- BATCHED coherent loads (pipelined issue, single wait; rule #18 fence) ----
__device__ __forceinline__ void ld16_async(uint4& dst, const void* p) {
    asm volatile("global_load_dwordx4 %0, %1, off sc1" : "=v"(dst) : "v"(p));
}
__device__ __forceinline__ void ld4_async(u32& dst, const void* p) {
    asm volatile("global_load_dword %0, %1, off sc1" : "=v"(dst) : "v"(p));
}
__device__ __forceinline__ void wait_vm0() {
    asm volatile("s_waitcnt vmcnt(0)" ::: "memory");
    __builtin_amdgcn_sched_barrier(0);
}

// ---- symmetric all-report/all-poll barrier over 32 WGs ----
__device__ __forceinline__ void gbar32(u32* flags, u32 gen) {
    asm volatile("s_waitcnt vmcnt(0)" ::: "memory");
    __syncthreads();
    if (threadIdx.x == 0) st_sc1_u32(flags + (u32)blockIdx.x * 16, gen);
    const int i = threadIdx.x;
    if (i < 32 && i != (int)blockIdx.x) {
        while (ld_sc1_u32(flags + i * 16) < gen) {}
    }
    __syncthreads();
}

// ---------------- prep kernels ----------------

__global__ __launch_bounds__(256) void transpose_cvt(
    const float* __restrict__ src, u16* __restrict__ dst, int K, int N)
{
    __shared__ float tile[32][33];
    const int n0 = blockIdx.x * 32, k0 = blockIdx.y * 32;
    const int tx = threadIdx.x & 31, ty = threadIdx.x >> 5;
    #pragma unroll
    for (int j = 0; j < 32; j += 8)
        tile[ty + j][tx] = src[(size_t)(k0 + ty + j) * N + n0 + tx];
    __syncthreads();
    #pragma unroll
    for (int j = 0; j < 32; j += 8)
        dst[(size_t)(n0 + ty + j) * K + k0 + tx] = f2bf(tile[tx][ty + j]);
}

__global__ __launch_bounds__(256) void cvt_f32_bf16(
    const float* __restrict__ src, u16* __restrict__ dst)
{
    const size_t i = ((size_t)blockIdx.x * 256 + threadIdx.x) * 8;
    float4 v0 = *(const float4*)(src + i);
    float4 v1 = *(const float4*)(src + i + 4);
    uint4 pk;
    pk.x = (u32)f2bf(v0.x) | ((u32)f2bf(v0.y) << 16);
    pk.y = (u32)f2bf(v0.z) | ((u32)f2bf(v0.w) << 16);
    pk.z = (u32)f2bf(v1.x) | ((u32)f2bf(v1.y) << 16);
    pk.w = (u32)f2bf(v1.z) | ((u32)f2bf(v1.w) << 16);
    *(uint4*)(dst + i) = pk;
}

__global__ __launch_bounds__(128) void gather_emb_bf16(
    const int* __restrict__ idx, const float* __restrict__ emb, u16* __restrict__ out)
{
    const int r = blockIdx.x;
    const int token = idx[r];
    const int i = threadIdx.x * 4;
    float4 v = *(const float4*)(emb + (size_t)token * 512 + i);
    uint2 pk;
    pk.x = (u32)f2bf(v.x) | ((u32)f2bf(v.y) << 16);
    pk.y = (u32)f2bf(v.z) | ((u32)f2bf(v.w) << 16);
    *(uint2*)(out + (size_t)r * 512 + i) = pk;
}

__global__ __launch_bounds__(512) void init_state(u32* hg, u32* bar)
{
    const int i = blockIdx.x * 512 + threadIdx.x;
    hg[i] = 0u;
    if (blockIdx.x < 2) bar[blockIdx.x * 512 + threadIdx.x] = 0u;
}

// ---------------- MFMA GEMM:  C[M,N](f32) = A[M,K](bf16) * BT[N,K](bf16) + bias ----------------
__global__ __launch_bounds__(256) void gemm_bf16(
    const u16* __restrict__ A, const u16* __restrict__ BT,
    const float* __restrict__ bias, float* __restrict__ C,
    int M, int N, int K)
{
    __shared__ __align__(16) u16 As[128][40];
    __shared__ __align__(16) u16 Bs[128][40];
    const int tid  = threadIdx.x;
    const int lane = tid & 63, wave = tid >> 6;
    const int wm = (wave & 1) * 64, wn = (wave >> 1) * 64;
    const int lrow = lane & 15, lk = (lane >> 4) * 8;
    const int srow = tid >> 2, skof = (tid & 3) * 8;
    const size_t K_ = (size_t)K;
    const u16* Ag = A + ((size_t)blockIdx.y * 128 + srow) * K_ + skof;
    const u16* Bg = BT + ((size_t)blockIdx.x * 128 + srow) * K_ + skof;
    f32x4 acc[4][4] = {};
    for (int k0 = 0; k0 < K; k0 += 32) {
        uint4 a0 = *(const uint4*)(Ag + k0);
        uint4 a1 = *(const uint4*)(Ag + 64 * K_ + k0);
        uint4 b0 = *(const uint4*)(Bg + k0);
        uint4 b1 = *(const uint4*)(Bg + 64 * K_ + k0);
        __syncthreads();
        *(uint4*)&As[srow][skof]      = a0;
        *(uint4*)&As[srow + 64][skof] = a1;
        *(uint4*)&Bs[srow][skof]      = b0;
        *(uint4*)&Bs[srow + 64][skof] = b1;
        __syncthreads();
        short8 af[4], bf[4];
        #pragma unroll
        for (int i = 0; i < 4; ++i) af[i] = *(const short8*)&As[wm + i * 16 + lrow][lk];
        #pragma unroll
        for (int j = 0; j < 4; ++j) bf[j] = *(const short8*)&Bs[wn + j * 16 + lrow][lk];
        #pragma unroll
        for (int i = 0; i < 4; ++i)
            #pragma unroll
            for (int j = 0; j < 4; ++j)
                acc[i][j] = __builtin_amdgcn_mfma_f32_16x16x32_bf16(af[i], bf[j], acc[i][j], 0, 0, 0);
    }
    const int crow0 = blockIdx.y * 128 + wm + (lane >> 4) * 4;
    const int ccol0 = blockIdx.x * 128 + wn + (lane & 15);
    #pragma unroll
    for (int j = 0; j < 4; ++j) {
        const float bv = bias ? bias[ccol0 + j * 16] : 0.f;
        #pragma unroll
        for (int i = 0; i < 4; ++i)
            #pragma unroll
            for (int rr = 0; rr < 4; ++rr)
                C[(size_t)(crow0 + i * 16 + rr) * N + (ccol0 + j * 16)] = acc[i][j][rr] + bv;
    }
}

// ============ persistent encoder: 32 WGs, LDS weights, coalesced exchanges ============
__global__ __launch_bounds__(512) void enc_coop(
    const float* __restrict__ gx, const u16* __restrict__ Urz, const u16* __restrict__ Un,
    const float* __restrict__ brz, const float* __restrict__ bn,
    u32* __restrict__ hg, u32* __restrict__ rhg, u32* __restrict__ zg,
    u16* __restrict__ enc_hs, u16* __restrict__ spack,
    u32* __restrict__ flags)
{
    const int w = blockIdx.x, tid = threadIdx.x;
    const int v = tid >> 6, lane = tid & 63;
    const int nl = lane & 15, kq = lane >> 4;
    __shared__ __align__(16) u16 UrzS[32][520];
    __shared__ __align__(16) u16 UnS[16][520];
    for (int idx = tid; idx < 32 * 64; idx += 512) {
        const int r = idx >> 6, c = idx & 63;
        *(uint4*)&UrzS[r][c * 8] = *(const uint4*)(Urz + (size_t)(w * 32 + r) * 512 + c * 8);
    }
    for (int idx = tid; idx < 16 * 64; idx += 512) {
        const int r = idx >> 6, c = idx & 63;
        *(uint4*)&UnS[r][c * 8] = *(const uint4*)(Un + (size_t)(w * 16 + r) * 512 + c * 8);
    }
    __syncthreads();
    for (int t = 0; t < SEQ; ++t) {
        const u32* hgA = hg + (t & 1) * 8192;
        u32*       hgW = hg + ((t + 1) & 1) * 8192;
        const u64* hq  = (const u64*)hgA;
        const u64* rq  = (const u64*)rhg;
        // ---- E1: h@Urz (waves 0..3) ----
        if (v < 4) {
            const int bt = v & 1, tl = v >> 1;
            const int n = w * 32 + tl * 16 + nl;
            const int brow = bt * 16 + nl;
            uint4 a[16]; u32 hvp[4];
            const u64* ab = hq + brow * 128 + kq * 2;
            #pragma unroll
            for (int i = 0; i < 16; ++i) ld16_async(a[i], ab + i * 8);
            #pragma unroll
            for (int rr = 0; rr < 4; ++rr)
                ld4_async(hvp[rr], hgA + (bt * 16 + kq * 4 + rr) * 256 + (n >> 1));
            float gxr_pf[4];
            #pragma unroll
            for (int rr = 0; rr < 4; ++rr) {
                const int b = bt * 16 + kq * 4 + rr;
                gxr_pf[rr] = gx[((size_t)(b * SEQ + t)) * 1536 + n];
            }
            wait_vm0();
            const u16* wl = &UrzS[tl * 16 + nl][0];
            f32x4 acc = {0.f, 0.f, 0.f, 0.f};
            #pragma unroll
            for (int i = 0; i < 16; ++i) {
                short8 bfv = *(const short8*)(wl + i * 32 + kq * 8);
                acc = __builtin_amdgcn_mfma_f32_16x16x32_bf16(
                    __builtin_bit_cast(short8, a[i]), bfv, acc, 0, 0, 0);
            }
            if (n < 512) {               // r gate -> rh
                u32 pk[4];
                #pragma unroll
                for (int rr = 0; rr < 4; ++rr) {
                    const float r = sigmoid_f(gxr_pf[rr] + acc[rr] + brz[n]);
                    const float hold = bf2f((u16)((n & 1) ? (hvp[rr] >> 16) : (hvp[rr] & 0xFFFF)));
                    pk[rr] = (u32)f2bf(r * hold);
                }
                #pragma unroll
                for (int rr = 0; rr < 4; ++rr) {
                    u32 oth = (u32)__shfl_xor((int)pk[rr], 1);
                    if ((n & 1) == 0) {
                        const int b = bt * 16 + kq * 4 + rr;
                        st_sc1_u32(rhg + b * 256 + (n >> 1), (pk[rr] & 0xFFFF) | (oth << 16));
                    }
                }
            } else {                     // z gate  (zg layout: [b][512])
                #pragma unroll
                for (int rr = 0; rr < 4; ++rr) {
                    const int b = bt * 16 + kq * 4 + rr;
                    const float z = sigmoid_f(gxr_pf[rr] + acc[rr] + brz[n]);
                    st_sc1_u32(zg + b * 512 + (n - 512), __float_as_uint(z));
                }
            }
        }
        gbar32(flags, (u32)(2 * t + 1));
        // ---- E2: (r*h)@Un, h update (waves 0..1) ----
        if (v < 2) {
            const int bt = v;
            const int n = w * 16 + nl;
            const int brow = bt * 16 + nl;
            uint4 a[16]; u32 hvp[4], zvp[4];
            const u64* ab = rq + brow * 128 + kq * 2;
            #pragma unroll
            for (int i = 0; i < 16; ++i) ld16_async(a[i], ab + i * 8);
            #pragma unroll
            for (int rr = 0; rr < 4; ++rr) {
                const int b = bt * 16 + kq * 4 + rr;
                ld4_async(hvp[rr], hgA + b * 256 + (n >> 1));
                ld4_async(zvp[rr], zg + b * 512 + n);
            }
            float gxr_pf[4];
            #pragma unroll
            for (int rr = 0; rr < 4; ++rr) {
                const int b = bt * 16 + kq * 4 + rr;
                gxr_pf[rr] = gx[((size_t)(b * SEQ + t)) * 1536 + 1024 + n];
            }
            wait_vm0();
            const u16* wl = &UnS[nl][0];
            f32x4 acc = {0.f, 0.f, 0.f, 0.f};
            #pragma unroll
            for (int i = 0; i < 16; ++i) {
                short8 bfv = *(const short8*)(wl + i * 32 + kq * 8);
                acc = __builtin_amdgcn_mfma_f32_16x16x32_bf16(
                    __builtin_bit_cast(short8, a[i]), bfv, acc, 0, 0, 0);
            }
            u32 pk[4];
            #pragma unroll
            for (int rr = 0; rr < 4; ++rr) {
                const int b = bt * 16 + kq * 4 + rr;
                const float nn = tanh_f(gxr_pf[rr] + acc[rr] + bn[n]);
                const float z = __uint_as_float(zvp[rr]);
                const float hold = bf2f((u16)((n & 1) ? (hvp[rr] >> 16) : (hvp[rr] & 0xFFFF)));
                const float hn = (1.f - z) * hold + z * nn;
                const u16 hb = f2bf(hn);
                pk[rr] = (u32)hb;
                enc_hs[((size_t)(b * SEQ + t)) * 512 + n] = hb;
                spack[(((size_t)b * 16 + (t >> 3)) * 512 + n) * 8 + (t & 7)] = hb;
            }
            #pragma unroll
            for (int rr = 0; rr < 4; ++rr) {
                u32 oth = (u32)__shfl_xor((int)pk[rr], 1);
                if ((n & 1) == 0) {
                    const int b = bt * 16 + kq * 4 + rr;
                    st_sc1_u32(hgW + b * 256 + (n >> 1), (pk[rr] & 0xFFFF) | (oth << 16));
                }
            }
        }
        gbar32(flags, (u32)(2 * t + 2));
    }
}

// ============ persistent decoder: 32 WGs, LDS weights, coalesced exchanges ============
__global__ __launch_bounds__(512) void dec_coop(
    const float* __restrict__ gxe, const u16* __restrict__ wh_bf, const u16* __restrict__ spack,
    const float* __restrict__ attn_v, const float* __restrict__ brz, const float* __restrict__ bn,
    const u16* __restrict__ Urz, const u16* __restrict__ Ws,
    const u16* __restrict__ WxC, const u16* __restrict__ Un,
    u32* __restrict__ hg, u32* __restrict__ rhg, u32* __restrict__ ctxg,
    u32* __restrict__ zg, u32* __restrict__ gg, u32* __restrict__ aWsg,
    u16* __restrict__ hctx, u32* __restrict__ flags)
{
    const int w = blockIdx.x, tid = threadIdx.x;
    const int v = tid >> 6, lane = tid & 63;
    const int nl = lane & 15, kq = lane >> 4;
    __shared__ __align__(16) u16 UWsS[48][520];
    __shared__ __align__(16) u16 WxCS[48][520];
    __shared__ __align__(16) u16 UnS2[16][520];
    __shared__ float hWsL[4 * 132], redE[512], attnL[128];
    __shared__ u16 ctxL[512];
    for (int idx = tid; idx < 48 * 64; idx += 512) {
        const int r = idx >> 6, c = idx & 63;
        const int gcol = w * 48 + r;
        const u16* s0 = (gcol < 1024 ? Urz + (size_t)gcol * 512
                                     : Ws + (size_t)(gcol - 1024) * 512) + c * 8;
        *(uint4*)&UWsS[r][c * 8] = *(const uint4*)s0;
        *(uint4*)&WxCS[r][c * 8] = *(const uint4*)(WxC + (size_t)gcol * 512 + c * 8);
    }
    for (int idx = tid; idx < 16 * 64; idx += 512) {
        const int r = idx >> 6, c = idx & 63;
        *(uint4*)&UnS2[r][c * 8] = *(const uint4*)(Un + (size_t)(w * 16 + r) * 512 + c * 8);
    }
    __syncthreads();
    for (int t = 0; t < SEQ; ++t) {
        const u32* hgA = hg + (t & 1) * 8192;
        u32*       hgW = hg + ((t + 1) & 1) * 8192;
        const u64* hq  = (const u64*)hgA;
        const u64* rq  = (const u64*)rhg;
        const u64* cq  = (const u64*)ctxg;
        f32x4 aPk = {0.f, 0.f, 0.f, 0.f};
        // ---- P1: h@[Urz | Ws] (waves 0..5) ----
        if (v < 6) {
            const int bt = v & 1, tl = v >> 1;
            const int n = w * 48 + tl * 16 + nl;
            const int brow = bt * 16 + nl;
            uint4 a[16];
            const u64* ab = hq + brow * 128 + kq * 2;
            #pragma unroll
            for (int i = 0; i < 16; ++i) ld16_async(a[i], ab + i * 8);
            wait_vm0();
            const u16* wl = &UWsS[tl * 16 + nl][0];
            f32x4 acc = {0.f, 0.f, 0.f, 0.f};
            #pragma unroll
            for (int i = 0; i < 16; ++i) {
                short8 bfv = *(const short8*)(wl + i * 32 + kq * 8);
                acc = __builtin_amdgcn_mfma_f32_16x16x32_bf16(
                    __builtin_bit_cast(short8, a[i]), bfv, acc, 0, 0, 0);
            }
            if (n < 1024) {
                aPk = acc;               // persists in regs to P3
            } else {                     // aWsg layout: [b][512]
                #pragma unroll
                for (int rr = 0; rr < 4; ++rr) {
                    const int b = bt * 16 + kq * 4 + rr;
                    st_sc1_u32(aWsg + b * 512 + (n - 1024), __float_as_uint(acc[rr]));
                }
            }
        }
        gbar32(flags, (u32)(4 * t + 1));
        // ---- P2: attention (all 32 WGs, b = w) ----
        {
            const int b = w;
            {
                u32 hwv;
                ld4_async(hwv, aWsg + b * 512 + tid);   // fully coalesced
                wait_vm0();
                hWsL[(tid >> 7) * 132 + (tid & 127)] = __uint_as_float(hwv);
            }
            __syncthreads();
            {
                const int s = tid >> 2, q = tid & 3;
                const u16* whr = wh_bf + ((size_t)(b * SEQ + s)) * 512 + q * 128;
                const float* avq = attn_v + q * 128;
                const float* hwq = &hWsL[q * 132];
                float e = 0.f;
                #pragma unroll 4
                for (int i = 0; i < 128; i += 8) {
                    uint4 wv = *(const uint4*)(whr + i);
                    float4 h0 = *(const float4*)(hwq + i);
                    float4 h1 = *(const float4*)(hwq + i + 4);
                    float4 v0 = *(const float4*)(avq + i);
                    float4 v1 = *(const float4*)(avq + i + 4);
                    e += v0.x * tanh_f(bf2f((u16)(wv.x & 0xFFFF)) + h0.x)
                       + v0.y * tanh_f(bf2f((u16)(wv.x >> 16))    + h0.y)
                       + v0.z * tanh_f(bf2f((u16)(wv.y & 0xFFFF)) + h0.z)
                       + v0.w * tanh_f(bf2f((u16)(wv.y >> 16))    + h0.w)
                       + v1.x * tanh_f(bf2f((u16)(wv.z & 0xFFFF)) + h1.x)
                       + v1.y * tanh_f(bf2f((u16)(wv.z >> 16))    + h1.y)
                       + v1.z * tanh_f(bf2f((u16)(wv.w & 0xFFFF)) + h1.z)
                       + v1.w * tanh_f(bf2f((u16)(wv.w >> 16))    + h1.w);
                }
                redE[tid] = e;
            }
            __syncthreads();
            if (tid < 64) {
                float e0 = redE[4 * tid] + redE[4 * tid + 1] + redE[4 * tid + 2] + redE[4 * tid + 3];
                float e1 = redE[4 * (tid + 64)] + redE[4 * (tid + 64) + 1]
                         + redE[4 * (tid + 64) + 2] + redE[4 * (tid + 64) + 3];
                float m = fmaxf(e0, e1);
                for (int o = 32; o >= 1; o >>= 1) m = fmaxf(m, __shfl_xor(m, o));
                float p0 = fexp2((e0 - m) * 1.442695040888963f);
                float p1 = fexp2((e1 - m) * 1.442695040888963f);
                float ss = p0 + p1;
                for (int o = 32; o >= 1; o >>= 1) ss += __shfl_xor(ss, o);
                const float inv = frcp(ss);
                attnL[tid]      = p0 * inv;
                attnL[tid + 64] = p1 * inv;
            }
            __syncthreads();
            {
                const int d = tid;
                float cv = 0.f;
                const u16* sp = spack + ((size_t)b * 16 * 512 + d) * 8;
                #pragma unroll 4
                for (int sb = 0; sb < 16; ++sb) {
                    uint4 sv = *(const uint4*)(sp + (size_t)sb * 4096);
                    const float* al = &attnL[sb * 8];
                    cv += al[0] * bf2f((u16)(sv.x & 0xFFFF)) + al[1] * bf2f((u16)(sv.x >> 16))
                        + al[2] * bf2f((u16)(sv.y & 0xFFFF)) + al[3] * bf2f((u16)(sv.y >> 16))
                        + al[4] * bf2f((u16)(sv.z & 0xFFFF)) + al[5] * bf2f((u16)(sv.z >> 16))
                        + al[6] * bf2f((u16)(sv.w & 0xFFFF)) + al[7] * bf2f((u16)(sv.w >> 16));
                }
                const u16 cb = f2bf(cv);
                ctxL[d] = cb;
                hctx[((size_t)(b * SEQ + t)) * 1024 + 512 + d] = cb;
            }
            __syncthreads();
            if (tid < 256) {
                u32 pk = (u32)ctxL[2 * tid] | ((u32)ctxL[2 * tid + 1] << 16);
                st_sc1_u32(ctxg + b * 256 + tid, pk);
            }
        }
        gbar32(flags, (u32)(4 * t + 2));
        // ---- P3: ctx@WxC + gates (waves 0..5; aPk from P1) ----
        if (v < 6) {
            const int bt = v & 1, tl = v >> 1;
            const int n = w * 48 + tl * 16 + nl;
            const int brow = bt * 16 + nl;
            uint4 a[16]; u32 hvp[4];
            const u64* ab = cq + brow * 128 + kq * 2;
            #pragma unroll
            for (int i = 0; i < 16; ++i) ld16_async(a[i], ab + i * 8);
            #pragma unroll
            for (int rr = 0; rr < 4; ++rr)
                ld4_async(hvp[rr], hgA + (bt * 16 + kq * 4 + rr) * 256 + ((n & 511) >> 1));
            float gxr_pf[4];
            #pragma unroll
            for (int rr = 0; rr < 4; ++rr) {
                const int b = bt * 16 + kq * 4 + rr;
                gxr_pf[rr] = gxe[((size_t)(b * SEQ + t)) * 1536 + n];
            }
            wait_vm0();
            const u16* wl = &WxCS[tl * 16 + nl][0];
            f32x4 acc = {0.f, 0.f, 0.f, 0.f};
            #pragma unroll
            for (int i = 0; i < 16; ++i) {
                short8 bfv = *(const short8*)(wl + i * 32 + kq * 8);
                acc = __builtin_amdgcn_mfma_f32_16x16x32_bf16(
                    __builtin_bit_cast(short8, a[i]), bfv, acc, 0, 0, 0);
            }
            if (n < 512) {               // r gate -> rh
                u32 pk[4];
                #pragma unroll
                for (int rr = 0; rr < 4; ++rr) {
                    const float r = sigmoid_f(gxr_pf[rr] + acc[rr] + aPk[rr] + brz[n]);
                    const float hold = bf2f((u16)((n & 1) ? (hvp[rr] >> 16) : (hvp[rr] & 0xFFFF)));
                    pk[rr] = (u32)f2bf(r * hold);
                }
                #pragma unroll
                for (int rr = 0; rr < 4; ++rr) {
                    u32 oth = (u32)__shfl_xor((int)pk[rr], 1);
                    if ((n & 1) == 0) {
                        const int b = bt * 16 + kq * 4 + rr;
                        st_sc1_u32(rhg + b * 256 + (n >> 1), (pk[rr] & 0xFFFF) | (oth << 16));
                    }
                }
            } else if (n < 1024) {       // z gate  (zg layout: [b][512])
                #pragma unroll
                for (int rr = 0; rr < 4; ++rr) {
                    const int b = bt * 16 + kq * 4 + rr;
                    const float z = sigmoid_f(gxr_pf[rr] + acc[rr] + aPk[rr] + brz[n]);
                    st_sc1_u32(zg + b * 512 + (n - 512), __float_as_uint(z));
                }
            } else {                     // n-gate pre-activation  (gg layout: [b][512])
                #pragma unroll
                for (int rr = 0; rr < 4; ++rr) {
                    const int b = bt * 16 + kq * 4 + rr;
                    st_sc1_u32(gg + b * 512 + (n - 1024), __float_as_uint(gxr_pf[rr] + acc[rr]));
                }
            }
        }
        gbar32(flags, (u32)(4 * t + 3));
        // ---- P4: (r*h)@Un, h update (waves 0..1) ----
        if (v < 2) {
            const int bt = v;
            const int n = w * 16 + nl;
            const int brow = bt * 16 + nl;
            uint4 a[16]; u32 gvp[4], zvp[4], hvp[4];
            const u64* ab = rq + brow * 128 + kq * 2;
            #pragma unroll
            for (int i = 0; i < 16; ++i) ld16_async(a[i], ab + i * 8);
            #pragma unroll
            for (int rr = 0; rr < 4; ++rr) {
                const int b = bt * 16 + kq * 4 + rr;
                ld4_async(gvp[rr], gg + b * 512 + n);
                ld4_async(zvp[rr], zg + b * 512 + n);
                ld4_async(hvp[rr], hgA + b * 256 + (n >> 1));
            }
            wait_vm0();
            const u16* wl = &UnS2[nl][0];
            f32x4 acc = {0.f, 0.f, 0.f, 0.f};
            #pragma unroll
            for (int i = 0; i < 16; ++i) {
                short8 bfv = *(const short8*)(wl + i * 32 + kq * 8);
                acc = __builtin_amdgcn_mfma_f32_16x16x32_bf16(
                    __builtin_bit_cast(short8, a[i]), bfv, acc, 0, 0, 0);
            }
            u32 pk[4];
            #pragma unroll
            for (int rr = 0; rr < 4; ++rr) {
                const int b = bt * 16 + kq * 4 + rr;
                const float nn = tanh_f(__uint_as_float(gvp[rr]) + acc[rr] + bn[n]);
                const float z = __uint_as_float(zvp[rr]);
                const float hold = bf2f((u16)((n & 1) ? (hvp[rr] >> 16) : (hvp[rr] & 0xFFFF)));
                const float hn = (1.f - z) * hold + z * nn;
                const u16 hb = f2bf(hn);
                pk[rr] = (u32)hb;
                hctx[((size_t)(b * SEQ + t)) * 1024 + n] = hb;
            }
            #pragma unroll
            for (int rr = 0; rr < 4; ++rr) {
                u32 oth = (u32)__shfl_xor((int)pk[rr], 1);
                if ((n & 1) == 0) {
                    const int b = bt * 16 + kq * 4 + rr;
                    st_sc1_u32(hgW + b * 256 + (n >> 1), (pk[rr] & 0xFFFF) | (oth << 16));
                }
            }
        }
        gbar32(flags, (u32)(4 * t + 4));
    }
}

// ---------------- log_softmax: 2-pass (online max+sum), in-place on [4096, 32000] ----------------
__global__ __launch_bounds__(256) void log_softmax_rows(float* __restrict__ out)
{
    const int row = blockIdx.x, tid = threadIdx.x;
    float* p = out + (size_t)row * VTOK;
    __shared__ float rbM[4], rbS[4];
    const float L2E = 1.442695040888963f;
    float m = -3.0e38f, s = 0.f;
    for (int i = tid * 4; i < VTOK; i += 1024) {
        float4 v = *(const float4*)(p + i);
        float lm = fmaxf(fmaxf(v.x, v.y), fmaxf(v.z, v.w));
        float nm = fmaxf(m, lm);
        s = s * fexp2((m - nm) * L2E)
          + fexp2((v.x - nm) * L2E) + fexp2((v.y - nm) * L2E)
          + fexp2((v.z - nm) * L2E) + fexp2((v.w - nm) * L2E);
        m = nm;
    }
    for (int o = 32; o >= 1; o >>= 1) {
        float om = __shfl_xor(m, o), os = __shfl_xor(s, o);
        float nm = fmaxf(m, om);
        s = s * fexp2((m - nm) * L2E) + os * fexp2((om - nm) * L2E);
        m = nm;
    }
    if ((tid & 63) == 0) { rbM[tid >> 6] = m; rbS[tid >> 6] = s; }
    __syncthreads();
    {
        float fm = fmaxf(fmaxf(rbM[0], rbM[1]), fmaxf(rbM[2], rbM[3]));
        float fs = rbS[0] * fexp2((rbM[0] - fm) * L2E) + rbS[1] * fexp2((rbM[1] - fm) * L2E)
                 + rbS[2] * fexp2((rbM[2] - fm) * L2E) + rbS[3] * fexp2((rbM[3] - fm) * L2E);
        m = fm; s = fs;
    }
    const float lse = m + __builtin_amdgcn_logf(s) * 0.6931471805599453f;
    for (int i = tid * 4; i < VTOK; i += 1024) {
        float4 v = *(const float4*)(p + i);
        v.x -= lse; v.y -= lse; v.z -= lse; v.w -= lse;
        *(float4*)(p + i) = v;
    }
}

// ---------------- host launcher ----------------
extern "C" void kernel_launch(void* const* d_in, const int* in_sizes, int n_in,
                              void* d_out, int out_size, void* d_ws, size_t ws_size,
                              hipStream_t stream)
{
    (void)in_sizes; (void)n_in; (void)out_size; (void)ws_size;
    const int*   src       = (const int*)  d_in[0];
    const int*   tgt       = (const int*)  d_in[1];
    const float* enc_embed = (const float*)d_in[2];
    const float* enc_Wx    = (const float*)d_in[3];
    const float* enc_bx    = (const float*)d_in[4];
    const float* enc_Urz   = (const float*)d_in[5];
    const float* enc_brz   = (const float*)d_in[6];
    const float* enc_Un    = (const float*)d_in[7];
    const float* enc_bn    = (const float*)d_in[8];
    const float* dec_embed = (const float*)d_in[9];
    const float* dec_Wx    = (const float*)d_in[10];
    const float* dec_bx    = (const float*)d_in[11];
    const float* dec_Urz   = (const float*)d_in[12];
    const float* dec_brz   = (const float*)d_in[13];
    const float* dec_Un    = (const float*)d_in[14];
    const float* dec_bn    = (const float*)d_in[15];
    const float* attn_Wh   = (const float*)d_in[16];
    const float* attn_Ws   = (const float*)d_in[17];
    const float* attn_v    = (const float*)d_in[18];
    const float* out_W     = (const float*)d_in[19];
    const float* out_b     = (const float*)d_in[20];

    // --- scratch in d_out (524,288,000 B); all dead before the final GEMM overwrites ---
    char* ob = (char*)d_out;
    float* gx_enc   = (float*)(ob + 0);
    float* gxe_dec  = (float*)(ob + 25165824);
    float* wh_enc   = (float*)(ob + 50331648);
    u16*   Aenc     = (u16*)(ob + 58720256);
    u16*   Adec     = (u16*)(ob + 62914560);
    u16*   enc_hs   = (u16*)(ob + 67108864);
    u16*   spack    = (u16*)(ob + 71303168);
    u16*   wh_bf    = (u16*)(ob + 75497472);
    u16*   encWxT   = (u16*)(ob + 79691776);
    u16*   decWxET  = (u16*)(ob + 81264640);
    u16*   WhT      = (u16*)(ob + 82837504);
    u16*   UrzET    = (u16*)(ob + 83361792);
    u16*   UnET     = (u16*)(ob + 84410368);
    u16*   UrzDT    = (u16*)(ob + 84934656);
    u16*   UnDT     = (u16*)(ob + 85983232);
    u16*   WsT      = (u16*)(ob + 86507520);
    u16*   WxCT     = (u16*)(ob + 87031808);
    u32*   hg       = (u32*)(ob + 88604672);
    u32*   rhg      = (u32*)(ob + 88670208);
    u32*   ctxg     = (u32*)(ob + 88702976);
    u32*   zg       = (u32*)(ob + 88735744);
    u32*   gg       = (u32*)(ob + 88801280);
    u32*   aWsg     = (u32*)(ob + 88866816);
    u32*   barp     = (u32*)(ob + 88932352);

    // --- d_ws: only what must coexist with the final GEMM's output ---
    char* wb = (char*)d_ws;
    u16* outWT = (u16*)(wb + 0);
    u16* hctx  = (u16*)(wb + 65536000);

    transpose_cvt<<<dim3(48, 16),   256, 0, stream>>>(enc_Wx,  encWxT, 512, 1536);
    transpose_cvt<<<dim3(48, 16),   256, 0, stream>>>(dec_Wx,  decWxET,512, 1536);
    transpose_cvt<<<dim3(16, 16),   256, 0, stream>>>(attn_Wh, WhT,    512, 512);
    transpose_cvt<<<dim3(1000, 32), 256, 0, stream>>>(out_W,   outWT, 1024, 32000);
    transpose_cvt<<<dim3(32, 16),   256, 0, stream>>>(enc_Urz, UrzET,  512, 1024);
    transpose_cvt<<<dim3(16, 16),   256, 0, stream>>>(enc_Un,  UnET,   512, 512);
    transpose_cvt<<<dim3(32, 16),   256, 0, stream>>>(dec_Urz, UrzDT,  512, 1024);
    transpose_cvt<<<dim3(16, 16),   256, 0, stream>>>(dec_Un,  UnDT,   512, 512);
    transpose_cvt<<<dim3(16, 16),   256, 0, stream>>>(attn_Ws, WsT,    512, 512);
    transpose_cvt<<<dim3(48, 16),   256, 0, stream>>>(dec_Wx + (size_t)512 * 1536, WxCT, 512, 1536);
    gather_emb_bf16<<<4096, 128, 0, stream>>>(src, enc_embed, Aenc);
    gather_emb_bf16<<<4096, 128, 0, stream>>>(tgt, dec_embed, Adec);

    gemm_bf16<<<dim3(12, 32), 256, 0, stream>>>(Aenc, encWxT,  enc_bx, gx_enc,  4096, 1536, 512);
    gemm_bf16<<<dim3(12, 32), 256, 0, stream>>>(Adec, decWxET, dec_bx, gxe_dec, 4096, 1536, 512);

    init_state<<<32, 512, 0, stream>>>(hg, barp);

    // encoder (persistent, 32 WGs, LDS weights)
    {
        u32* encF = barp;
        void* args[] = { (void*)&gx_enc, (void*)&UrzET, (void*)&UnET, (void*)&enc_brz,
                         (void*)&enc_bn, (void*)&hg, (void*)&rhg, (void*)&zg,
                         (void*)&enc_hs, (void*)&spack, (void*)&encF };
        hipLaunchCooperativeKernel((void*)enc_coop, dim3(32), dim3(512), args, 0, stream);
    }

    gemm_bf16<<<dim3(4, 32), 256, 0, stream>>>(enc_hs, WhT, nullptr, wh_enc, 4096, 512, 512);
    cvt_f32_bf16<<<1024, 256, 0, stream>>>(wh_enc, wh_bf);

    // decoder (persistent, 32 WGs, LDS weights; h carried in hg parity 0)
    {
        u32* decF = barp + 512;
        void* args[] = { (void*)&gxe_dec, (void*)&wh_bf, (void*)&spack, (void*)&attn_v,
                         (void*)&dec_brz, (void*)&dec_bn, (void*)&UrzDT, (void*)&WsT,
                         (void*)&WxCT, (void*)&UnDT, (void*)&hg, (void*)&rhg, (void*)&ctxg,
                         (void*)&zg, (void*)&gg, (void*)&aWsg, (void*)&hctx, (void*)&decF };
        hipLaunchCooperativeKernel((void*)dec_coop, dim3(32), dim3(512), args, 0, stream);
    }

    gemm_bf16<<<dim3(250, 32), 256, 0, stream>>>(hctx, outWT, out_b, (float*)d_out, 4096, VTOK, 1024);
    log_softmax_rows<<<4096, 256, 0, stream>>>((float*)d_out);
}

// Round 13
// 5167.166 us; speedup vs baseline: 1.3014x; 1.0522x over previous
//
#include <hip/hip_runtime.h>
#include <stdint.h>

#define BATCH 32
#define SEQ   128       // S == T == 128
#define HID   512
#define VTOK  32000
#define NTILES 8000     // 32 row-tiles x 250 col-tiles of the output projection

typedef unsigned short u16;
typedef unsigned int   u32;
typedef unsigned long long u64;
typedef float    f32x4  __attribute__((ext_vector_type(4)));
typedef short    short8 __attribute__((ext_vector_type(8)));

__device__ __forceinline__ u16 f2bf(float f) {
    u32 u = __builtin_bit_cast(u32, f);
    return (u16)((u + 0x7FFFu + ((u >> 16) & 1u)) >> 16);
}
__device__ __forceinline__ float bf2f(u16 v) {
    u32 u = ((u32)v) << 16; return __builtin_bit_cast(float, u);
}
__device__ __forceinline__ float fexp2(float x) { return __builtin_amdgcn_exp2f(x); }
__device__ __forceinline__ float frcp(float x)  { return __builtin_amdgcn_rcpf(x); }
__device__ __forceinline__ float sigmoid_f(float x) {
    return frcp(1.f + fexp2(-1.442695040888963f * x));
}
__device__ __forceinline__ float tanh_f(float x) {
    return 1.f - 2.f * frcp(1.f + fexp2(2.885390081777927f * x));
}

// ---- LLC-coherent (sc1) relaxed atomics ----
__device__ __forceinline__ u32 ld_sc1_u32(const u32* p) {
    return __hip_atomic_load(p, __ATOMIC_RELAXED, __HIP_MEMORY_SCOPE_AGENT);
}
__device__ __forceinline__ void st_sc1_u32(u32* p, u32 v) {
    __hip_atomic_store(p, v, __ATOMIC_RELAXED, __HIP_MEMORY_SCOPE_AGENT);
}

// ---- BATCHED coherent loads (pipelined issue, single wait; rule #18 fence) ----
__device__ __forceinline__ void ld16_async(uint4& dst, const void* p) {
    asm volatile("global_load_dwordx4 %0, %1, off sc1" : "=v"(dst) : "v"(p));
}
__device__ __forceinline__ void ld4_async(u32& dst, const void* p) {
    asm volatile("global_load_dword %0, %1, off sc1" : "=v"(dst) : "v"(p));
}
__device__ __forceinline__ void wait_vm0() {
    asm volatile("s_waitcnt vmcnt(0)" ::: "memory");
    __builtin_amdgcn_sched_barrier(0);
}

// ---- symmetric all-report/all-poll barrier over 32 WGs ----
__device__ __forceinline__ void gbar32(u32* flags, u32 gen) {
    asm volatile("s_waitcnt vmcnt(0)" ::: "memory");
    __syncthreads();
    if (threadIdx.x == 0) st_sc1_u32(flags + (u32)blockIdx.x * 16, gen);
    const int i = threadIdx.x;
    if (i < 32 && i != (int)blockIdx.x) {
        while (ld_sc1_u32(flags + i * 16) < gen) {}
    }
    __syncthreads();
}

// ---------------- prep kernels ----------------

__global__ __launch_bounds__(256) void transpose_cvt(
    const float* __restrict__ src, u16* __restrict__ dst, int K, int N)
{
    __shared__ float tile[32][33];
    const int n0 = blockIdx.x * 32, k0 = blockIdx.y * 32;
    const int tx = threadIdx.x & 31, ty = threadIdx.x >> 5;
    #pragma unroll
    for (int j = 0; j < 32; j += 8)
        tile[ty + j][tx] = src[(size_t)(k0 + ty + j) * N + n0 + tx];
    __syncthreads();
    #pragma unroll
    for (int j = 0; j < 32; j += 8)
        dst[(size_t)(n0 + ty + j) * K + k0 + tx] = f2bf(tile[tx][ty + j]);
}

__global__ __launch_bounds__(256) void cvt_f32_bf16(
    const float* __restrict__ src, u16* __restrict__ dst)
{
    const size_t i = ((size_t)blockIdx.x * 256 + threadIdx.x) * 8;
    float4 v0 = *(const float4*)(src + i);
    float4 v1 = *(const float4*)(src + i + 4);
    uint4 pk;
    pk.x = (u32)f2bf(v0.x) | ((u32)f2bf(v0.y) << 16);
    pk.y = (u32)f2bf(v0.z) | ((u32)f2bf(v0.w) << 16);
    pk.z = (u32)f2bf(v1.x) | ((u32)f2bf(v1.y) << 16);
    pk.w = (u32)f2bf(v1.z) | ((u32)f2bf(v1.w) << 16);
    *(uint4*)(dst + i) = pk;
}

// gxe f32 [b*128+t][1536] -> bf16 [t*32+b][1536]
__global__ __launch_bounds__(192) void repack_gxe(
    const float* __restrict__ src, u16* __restrict__ dst)
{
    const int r = blockIdx.x;                 // b*128+t
    const int b = r >> 7, t = r & 127;
    const float* s = src + (size_t)r * 1536;
    u16* d = dst + ((size_t)(t * 32 + b)) * 1536;
    const int i = threadIdx.x * 8;
    float4 v0 = *(const float4*)(s + i);
    float4 v1 = *(const float4*)(s + i + 4);
    uint4 pk;
    pk.x = (u32)f2bf(v0.x) | ((u32)f2bf(v0.y) << 16);
    pk.y = (u32)f2bf(v0.z) | ((u32)f2bf(v0.w) << 16);
    pk.z = (u32)f2bf(v1.x) | ((u32)f2bf(v1.y) << 16);
    pk.w = (u32)f2bf(v1.z) | ((u32)f2bf(v1.w) << 16);
    *(uint4*)(d + i) = pk;
}

__global__ __launch_bounds__(128) void gather_emb_bf16(
    const int* __restrict__ idx, const float* __restrict__ emb, u16* __restrict__ out)
{
    const int r = blockIdx.x;
    const int token = idx[r];
    const int i = threadIdx.x * 4;
    float4 v = *(const float4*)(emb + (size_t)token * 512 + i);
    uint2 pk;
    pk.x = (u32)f2bf(v.x) | ((u32)f2bf(v.y) << 16);
    pk.y = (u32)f2bf(v.z) | ((u32)f2bf(v.w) << 16);
    *(uint2*)(out + (size_t)r * 512 + i) = pk;
}

// zero h (16384 u32) + ctrl block (2048 u32: flags, progress, tile counter)
__global__ __launch_bounds__(512) void init_state(u32* hg, u32* ctrl)
{
    const int i = blockIdx.x * 512 + threadIdx.x;
    hg[i] = 0u;
    if (blockIdx.x < 4) ctrl[blockIdx.x * 512 + threadIdx.x] = 0u;
}

// ---------------- MFMA GEMM:  C[M,N](f32) = A[M,K](bf16) * BT[N,K](bf16) + bias ----------------
// rperm=1: output row remap r -> (r&31)*128 + (r>>5)   (hctx [t*32+b] -> logits [b*128+t])
__global__ __launch_bounds__(256) void gemm_bf16(
    const u16* __restrict__ A, const u16* __restrict__ BT,
    const float* __restrict__ bias, float* __restrict__ C,
    int M, int N, int K, int rperm)
{
    __shared__ __align__(16) u16 As[128][40];
    __shared__ __align__(16) u16 Bs[128][40];
    const int tid  = threadIdx.x;
    const int lane = tid & 63, wave = tid >> 6;
    const int wm = (wave & 1) * 64, wn = (wave >> 1) * 64;
    const int lrow = lane & 15, lk = (lane >> 4) * 8;
    const int srow = tid >> 2, skof = (tid & 3) * 8;
    const size_t K_ = (size_t)K;
    const u16* Ag = A + ((size_t)blockIdx.y * 128 + srow) * K_ + skof;
    const u16* Bg = BT + ((size_t)blockIdx.x * 128 + srow) * K_ + skof;
    f32x4 acc[4][4] = {};
    for (int k0 = 0; k0 < K; k0 += 32) {
        uint4 a0 = *(const uint4*)(Ag + k0);
        uint4 a1 = *(const uint4*)(Ag + 64 * K_ + k0);
        uint4 b0 = *(const uint4*)(Bg + k0);
        uint4 b1 = *(const uint4*)(Bg + 64 * K_ + k0);
        __syncthreads();
        *(uint4*)&As[srow][skof]      = a0;
        *(uint4*)&As[srow + 64][skof] = a1;
        *(uint4*)&Bs[srow][skof]      = b0;
        *(uint4*)&Bs[srow + 64][skof] = b1;
        __syncthreads();
        short8 af[4], bf[4];
        #pragma unroll
        for (int i = 0; i < 4; ++i) af[i] = *(const short8*)&As[wm + i * 16 + lrow][lk];
        #pragma unroll
        for (int j = 0; j < 4; ++j) bf[j] = *(const short8*)&Bs[wn + j * 16 + lrow][lk];
        #pragma unroll
        for (int i = 0; i < 4; ++i)
            #pragma unroll
            for (int j = 0; j < 4; ++j)
                acc[i][j] = __builtin_amdgcn_mfma_f32_16x16x32_bf16(af[i], bf[j], acc[i][j], 0, 0, 0);
    }
    const int crow0 = blockIdx.y * 128 + wm + (lane >> 4) * 4;
    const int ccol0 = blockIdx.x * 128 + wn + (lane & 15);
    #pragma unroll
    for (int j = 0; j < 4; ++j) {
        const float bv = bias ? bias[ccol0 + j * 16] : 0.f;
        #pragma unroll
        for (int i = 0; i < 4; ++i)
            #pragma unroll
            for (int rr = 0; rr < 4; ++rr) {
                int r = crow0 + i * 16 + rr;
                int orow = rperm ? ((r & 31) * 128 + (r >> 5)) : r;
                C[(size_t)orow * N + (ccol0 + j * 16)] = acc[i][j][rr] + bv;
            }
    }
}

// ---- output-projection tile worker: 512 threads, tiles 128x128, K=1024 ----
// hctx rows are [t*32+b]; logits written remapped to [b*128+t]. A reads sc1.
__device__ __forceinline__ void gemm_tiles(
    const u16* __restrict__ hctx, const u16* __restrict__ outWT,
    const float* __restrict__ out_b, float* __restrict__ C,
    u32* progress, u32* tctr, u16* lds, u32* wslot)
{
    const int tid = threadIdx.x;
    u16* As = lds;              // [128][40]
    u16* Bs = lds + 5120;       // [128][40]
    const int lane = tid & 63, wave = tid >> 6;
    const int wm = (wave & 1) * 64, wn = (wave >> 1) * 32;
    const int lrow = lane & 15, lk = (lane >> 4) * 8;
    const int srow = tid >> 2, skof = (tid & 3) * 8;
    for (;;) {
        if (tid == 0) *wslot = __hip_atomic_fetch_add(tctr, 1u, __ATOMIC_RELAXED, __HIP_MEMORY_SCOPE_AGENT);
        __syncthreads();
        const u32 k = *wslot;
        __syncthreads();
        if (k >= (u32)NTILES) break;
        const int rt = (int)(k / 250u), ct = (int)(k % 250u);
        if (tid == 0) {
            while (ld_sc1_u32(progress) < (u32)((rt + 1) * 4)) __builtin_amdgcn_s_sleep(8);
        }
        __syncthreads();
        const u16* Ag = hctx + ((size_t)(rt * 128 + srow)) * 1024 + skof;
        const u16* Bg = outWT + ((size_t)(ct * 128 + srow)) * 1024 + skof;
        f32x4 acc[4][2] = {};
        for (int k0 = 0; k0 < 1024; k0 += 32) {
            uint4 a0; ld16_async(a0, Ag + k0);
            uint4 b0 = *(const uint4*)(Bg + k0);
            wait_vm0();
            __syncthreads();
            *(uint4*)&As[srow * 40 + skof] = a0;
            *(uint4*)&Bs[srow * 40 + skof] = b0;
            __syncthreads();
            short8 af[4], bf[2];
            #pragma unroll
            for (int i = 0; i < 4; ++i) af[i] = *(const short8*)&As[(wm + i * 16 + lrow) * 40 + lk];
            #pragma unroll
            for (int j = 0; j < 2; ++j) bf[j] = *(const short8*)&Bs[(wn + j * 16 + lrow) * 40 + lk];
            #pragma unroll
            for (int i = 0; i < 4; ++i)
                #pragma unroll
                for (int j = 0; j < 2; ++j)
                    acc[i][j] = __builtin_amdgcn_mfma_f32_16x16x32_bf16(af[i], bf[j], acc[i][j], 0, 0, 0);
        }
        const int crow0 = rt * 128 + wm + (lane >> 4) * 4;
        const int ccol0 = ct * 128 + wn + (lane & 15);
        #pragma unroll
        for (int j = 0; j < 2; ++j) {
            const float bv = out_b[ccol0 + j * 16];
            #pragma unroll
            for (int i = 0; i < 4; ++i)
                #pragma unroll
                for (int rr = 0; rr < 4; ++rr) {
                    int r = crow0 + i * 16 + rr;
                    int orow = (r & 31) * 128 + (r >> 5);
                    C[(size_t)orow * VTOK + (ccol0 + j * 16)] = acc[i][j][rr] + bv;
                }
        }
    }
}

// ============ persistent encoder: 32 WGs, LDS weights, coalesced exchanges ============
__global__ __launch_bounds__(512) void enc_coop(
    const float* __restrict__ gx, const u16* __restrict__ Urz, const u16* __restrict__ Un,
    const float* __restrict__ brz, const float* __restrict__ bn,
    u32* __restrict__ hg, u32* __restrict__ rhg, u32* __restrict__ zg,
    u16* __restrict__ enc_hs, u16* __restrict__ spack,
    u32* __restrict__ flags)
{
    const int w = blockIdx.x, tid = threadIdx.x;
    const int v = tid >> 6, lane = tid & 63;
    const int nl = lane & 15, kq = lane >> 4;
    __shared__ __align__(16) u16 UrzS[32][520];
    __shared__ __align__(16) u16 UnS[16][520];
    for (int idx = tid; idx < 32 * 64; idx += 512) {
        const int r = idx >> 6, c = idx & 63;
        *(uint4*)&UrzS[r][c * 8] = *(const uint4*)(Urz + (size_t)(w * 32 + r) * 512 + c * 8);
    }
    for (int idx = tid; idx < 16 * 64; idx += 512) {
        const int r = idx >> 6, c = idx & 63;
        *(uint4*)&UnS[r][c * 8] = *(const uint4*)(Un + (size_t)(w * 16 + r) * 512 + c * 8);
    }
    __syncthreads();
    for (int t = 0; t < SEQ; ++t) {
        const u32* hgA = hg + (t & 1) * 8192;
        u32*       hgW = hg + ((t + 1) & 1) * 8192;
        const u64* hq  = (const u64*)hgA;
        const u64* rq  = (const u64*)rhg;
        // ---- E1: h@Urz (waves 0..3) ----
        if (v < 4) {
            const int bt = v & 1, tl = v >> 1;
            const int n = w * 32 + tl * 16 + nl;
            const int brow = bt * 16 + nl;
            uint4 a[16]; u32 hvp[4];
            const u64* ab = hq + brow * 128 + kq * 2;
            #pragma unroll
            for (int i = 0; i < 16; ++i) ld16_async(a[i], ab + i * 8);
            #pragma unroll
            for (int rr = 0; rr < 4; ++rr)
                ld4_async(hvp[rr], hgA + (bt * 16 + kq * 4 + rr) * 256 + (n >> 1));
            float gxr_pf[4];
            #pragma unroll
            for (int rr = 0; rr < 4; ++rr) {
                const int b = bt * 16 + kq * 4 + rr;
                gxr_pf[rr] = gx[((size_t)(b * SEQ + t)) * 1536 + n];
            }
            wait_vm0();
            const u16* wl = &UrzS[tl * 16 + nl][0];
            f32x4 acc = {0.f, 0.f, 0.f, 0.f};
            #pragma unroll
            for (int i = 0; i < 16; ++i) {
                short8 bfv = *(const short8*)(wl + i * 32 + kq * 8);
                acc = __builtin_amdgcn_mfma_f32_16x16x32_bf16(
                    __builtin_bit_cast(short8, a[i]), bfv, acc, 0, 0, 0);
            }
            if (n < 512) {
                u32 pk[4];
                #pragma unroll
                for (int rr = 0; rr < 4; ++rr) {
                    const float r = sigmoid_f(gxr_pf[rr] + acc[rr] + brz[n]);
                    const float hold = bf2f((u16)((n & 1) ? (hvp[rr] >> 16) : (hvp[rr] & 0xFFFF)));
                    pk[rr] = (u32)f2bf(r * hold);
                }
                #pragma unroll
                for (int rr = 0; rr < 4; ++rr) {
                    u32 oth = (u32)__shfl_xor((int)pk[rr], 1);
                    if ((n & 1) == 0) {
                        const int b = bt * 16 + kq * 4 + rr;
                        st_sc1_u32(rhg + b * 256 + (n >> 1), (pk[rr] & 0xFFFF) | (oth << 16));
                    }
                }
            } else {
                #pragma unroll
                for (int rr = 0; rr < 4; ++rr) {
                    const int b = bt * 16 + kq * 4 + rr;
                    const float z = sigmoid_f(gxr_pf[rr] + acc[rr] + brz[n]);
                    st_sc1_u32(zg + b * 512 + (n - 512), __float_as_uint(z));
                }
            }
        }
        gbar32(flags, (u32)(2 * t + 1));
        // ---- E2: (r*h)@Un, h update (waves 0..1) ----
        if (v < 2) {
            const int bt = v;
            const int n = w * 16 + nl;
            const int brow = bt * 16 + nl;
            uint4 a[16]; u32 hvp[4], zvp[4];
            const u64* ab = rq + brow * 128 + kq * 2;
            #pragma unroll
            for (int i = 0; i < 16; ++i) ld16_async(a[i], ab + i * 8);
            #pragma unroll
            for (int rr = 0; rr < 4; ++rr) {
                const int b = bt * 16 + kq * 4 + rr;
                ld4_async(hvp[rr], hgA + b * 256 + (n >> 1));
                ld4_async(zvp[rr], zg + b * 512 + n);
            }
            float gxr_pf[4];
            #pragma unroll
            for (int rr = 0; rr < 4; ++rr) {
                const int b = bt * 16 + kq * 4 + rr;
                gxr_pf[rr] = gx[((size_t)(b * SEQ + t)) * 1536 + 1024 + n];
            }
            wait_vm0();
            const u16* wl = &UnS[nl][0];
            f32x4 acc = {0.f, 0.f, 0.f, 0.f};
            #pragma unroll
            for (int i = 0; i < 16; ++i) {
                short8 bfv = *(const short8*)(wl + i * 32 + kq * 8);
                acc = __builtin_amdgcn_mfma_f32_16x16x32_bf16(
                    __builtin_bit_cast(short8, a[i]), bfv, acc, 0, 0, 0);
            }
            u32 pk[4];
            #pragma unroll
            for (int rr = 0; rr < 4; ++rr) {
                const int b = bt * 16 + kq * 4 + rr;
                const float nn = tanh_f(gxr_pf[rr] + acc[rr] + bn[n]);
                const float z = __uint_as_float(zvp[rr]);
                const float hold = bf2f((u16)((n & 1) ? (hvp[rr] >> 16) : (hvp[rr] & 0xFFFF)));
                const float hn = (1.f - z) * hold + z * nn;
                const u16 hb = f2bf(hn);
                pk[rr] = (u32)hb;
                enc_hs[((size_t)(b * SEQ + t)) * 512 + n] = hb;
                spack[(((size_t)b * 16 + (t >> 3)) * 512 + n) * 8 + (t & 7)] = hb;
            }
            #pragma unroll
            for (int rr = 0; rr < 4; ++rr) {
                u32 oth = (u32)__shfl_xor((int)pk[rr], 1);
                if ((n & 1) == 0) {
                    const int b = bt * 16 + kq * 4 + rr;
                    st_sc1_u32(hgW + b * 256 + (n >> 1), (pk[rr] & 0xFFFF) | (oth << 16));
                }
            }
        }
        gbar32(flags, (u32)(2 * t + 2));
    }
}

// ============ persistent decoder + in-flight output projection ============
__global__ __launch_bounds__(512) void dec_coop(
    const u16* __restrict__ gxe_bf, const u16* __restrict__ wh_bf, const u16* __restrict__ spack,
    const float* __restrict__ attn_v, const float* __restrict__ brz, const float* __restrict__ bn,
    const u16* __restrict__ Urz, const u16* __restrict__ Ws,
    const u16* __restrict__ WxC, const u16* __restrict__ Un,
    u32* __restrict__ hg, u32* __restrict__ rhg, u32* __restrict__ ctxg,
    u32* __restrict__ zg, u32* __restrict__ gg, u32* __restrict__ aWsg,
    u16* __restrict__ hctx, u32* __restrict__ flags,
    const u16* __restrict__ outWT, const float* __restrict__ out_b, float* __restrict__ Cout,
    u32* __restrict__ progress, u32* __restrict__ tctr, int do_gemm)
{
    const int w = blockIdx.x, tid = threadIdx.x;
    const int v = tid >> 6, lane = tid & 63;
    const int nl = lane & 15, kq = lane >> 4;
    __shared__ __align__(16) u16 UWsS[48][520];
    __shared__ __align__(16) u16 WxCS[48][520];
    __shared__ __align__(16) u16 UnS2[16][520];
    __shared__ float hWsL[4 * 132], redE[512], attnL[128];
    __shared__ u16 ctxL[512];
    __shared__ u32 wslotS;
    // ---- GEMM worker WGs ----
    if (w >= 32) {
        if (do_gemm)
            gemm_tiles(hctx, outWT, out_b, Cout, progress, tctr, &UWsS[0][0], &wslotS);
        return;
    }
    for (int idx = tid; idx < 48 * 64; idx += 512) {
        const int r = idx >> 6, c = idx & 63;
        const int gcol = w * 48 + r;
        const u16* s0 = (gcol < 1024 ? Urz + (size_t)gcol * 512
                                     : Ws + (size_t)(gcol - 1024) * 512) + c * 8;
        *(uint4*)&UWsS[r][c * 8] = *(const uint4*)s0;
        *(uint4*)&WxCS[r][c * 8] = *(const uint4*)(WxC + (size_t)gcol * 512 + c * 8);
    }
    for (int idx = tid; idx < 16 * 64; idx += 512) {
        const int r = idx >> 6, c = idx & 63;
        *(uint4*)&UnS2[r][c * 8] = *(const uint4*)(Un + (size_t)(w * 16 + r) * 512 + c * 8);
    }
    __syncthreads();
    for (int t = 0; t < SEQ; ++t) {
        const u32* hgA = hg + (t & 1) * 8192;
        u32*       hgW = hg + ((t + 1) & 1) * 8192;
        const u64* hq  = (const u64*)hgA;
        const u64* rq  = (const u64*)rhg;
        const u64* cq  = (const u64*)ctxg;
        f32x4 aPk = {0.f, 0.f, 0.f, 0.f};
        // ---- P1: h@[Urz | Ws] (waves 0..5) ----
        if (v < 6) {
            const int bt = v & 1, tl = v >> 1;
            const int n = w * 48 + tl * 16 + nl;
            const int brow = bt * 16 + nl;
            uint4 a[16];
            const u64* ab = hq + brow * 128 + kq * 2;
            #pragma unroll
            for (int i = 0; i < 16; ++i) ld16_async(a[i], ab + i * 8);
            wait_vm0();
            const u16* wl = &UWsS[tl * 16 + nl][0];
            f32x4 acc = {0.f, 0.f, 0.f, 0.f};
            #pragma unroll
            for (int i = 0; i < 16; ++i) {
                short8 bfv = *(const short8*)(wl + i * 32 + kq * 8);
                acc = __builtin_amdgcn_mfma_f32_16x16x32_bf16(
                    __builtin_bit_cast(short8, a[i]), bfv, acc, 0, 0, 0);
            }
            if (n < 1024) {
                aPk = acc;
            } else {
                #pragma unroll
                for (int rr = 0; rr < 4; ++rr) {
                    const int b = bt * 16 + kq * 4 + rr;
                    st_sc1_u32(aWsg + b * 512 + (n - 1024), __float_as_uint(acc[rr]));
                }
            }
        }
        gbar32(flags, (u32)(4 * t + 1));
        // ---- P2: attention (all 32 WGs, b = w) ----
        {
            const int b = w;
            {
                u32 hwv;
                ld4_async(hwv, aWsg + b * 512 + tid);
                wait_vm0();
                hWsL[(tid >> 7) * 132 + (tid & 127)] = __uint_as_float(hwv);
            }
            __syncthreads();
            {
                const int s = tid >> 2, q = tid & 3;
                const u16* whr = wh_bf + ((size_t)(b * SEQ + s)) * 512 + q * 128;
                const float* avq = attn_v + q * 128;
                const float* hwq = &hWsL[q * 132];
                float e = 0.f;
                #pragma unroll 4
                for (int i = 0; i < 128; i += 8) {
                    uint4 wv = *(const uint4*)(whr + i);
                    float4 h0 = *(const float4*)(hwq + i);
                    float4 h1 = *(const float4*)(hwq + i + 4);
                    float4 v0 = *(const float4*)(avq + i);
                    float4 v1 = *(const float4*)(avq + i + 4);
                    e += v0.x * tanh_f(bf2f((u16)(wv.x & 0xFFFF)) + h0.x)
                       + v0.y * tanh_f(bf2f((u16)(wv.x >> 16))    + h0.y)
                       + v0.z * tanh_f(bf2f((u16)(wv.y & 0xFFFF)) + h0.z)
                       + v0.w * tanh_f(bf2f((u16)(wv.y >> 16))    + h0.w)
                       + v1.x * tanh_f(bf2f((u16)(wv.z & 0xFFFF)) + h1.x)
                       + v1.y * tanh_f(bf2f((u16)(wv.z >> 16))    + h1.y)
                       + v1.z * tanh_f(bf2f((u16)(wv.w & 0xFFFF)) + h1.z)
                       + v1.w * tanh_f(bf2f((u16)(wv.w >> 16))    + h1.w);
                }
                redE[tid] = e;
            }
            __syncthreads();
            if (tid < 64) {
                float e0 = redE[4 * tid] + redE[4 * tid + 1] + redE[4 * tid + 2] + redE[4 * tid + 3];
                float e1 = redE[4 * (tid + 64)] + redE[4 * (tid + 64) + 1]
                         + redE[4 * (tid + 64) + 2] + redE[4 * (tid + 64) + 3];
                float m = fmaxf(e0, e1);
                for (int o = 32; o >= 1; o >>= 1) m = fmaxf(m, __shfl_xor(m, o));
                float p0 = fexp2((e0 - m) * 1.442695040888963f);
                float p1 = fexp2((e1 - m) * 1.442695040888963f);
                float ss = p0 + p1;
                for (int o = 32; o >= 1; o >>= 1) ss += __shfl_xor(ss, o);
                const float inv = frcp(ss);
                attnL[tid]      = p0 * inv;
                attnL[tid + 64] = p1 * inv;
            }
            __syncthreads();
            {
                const int d = tid;
                float cv = 0.f;
                const u16* sp = spack + ((size_t)b * 16 * 512 + d) * 8;
                #pragma unroll 4
                for (int sb = 0; sb < 16; ++sb) {
                    uint4 sv = *(const uint4*)(sp + (size_t)sb * 4096);
                    const float* al = &attnL[sb * 8];
                    cv += al[0] * bf2f((u16)(sv.x & 0xFFFF)) + al[1] * bf2f((u16)(sv.x >> 16))
                        + al[2] * bf2f((u16)(sv.y & 0xFFFF)) + al[3] * bf2f((u16)(sv.y >> 16))
                        + al[4] * bf2f((u16)(sv.z & 0xFFFF)) + al[5] * bf2f((u16)(sv.z >> 16))
                        + al[6] * bf2f((u16)(sv.w & 0xFFFF)) + al[7] * bf2f((u16)(sv.w >> 16));
                }
                ctxL[d] = f2bf(cv);
            }
            __syncthreads();
            if (tid < 256) {
                u32 pk = (u32)ctxL[2 * tid] | ((u32)ctxL[2 * tid + 1] << 16);
                st_sc1_u32(ctxg + b * 256 + tid, pk);
                st_sc1_u32((u32*)(hctx + ((size_t)(t * 32 + b)) * 1024 + 512) + tid, pk);
            }
        }
        gbar32(flags, (u32)(4 * t + 2));
        // ---- P3: ctx@WxC + gates (waves 0..5; aPk from P1) ----
        if (v < 6) {
            const int bt = v & 1, tl = v >> 1;
            const int n = w * 48 + tl * 16 + nl;
            const int brow = bt * 16 + nl;
            uint4 a[16]; u32 hvp[4];
            const u64* ab = cq + brow * 128 + kq * 2;
            #pragma unroll
            for (int i = 0; i < 16; ++i) ld16_async(a[i], ab + i * 8);
            #pragma unroll
            for (int rr = 0; rr < 4; ++rr)
                ld4_async(hvp[rr], hgA + (bt * 16 + kq * 4 + rr) * 256 + ((n & 511) >> 1));
            float gxr_pf[4];
            #pragma unroll
            for (int rr = 0; rr < 4; ++rr) {
                const int b = bt * 16 + kq * 4 + rr;
                gxr_pf[rr] = bf2f(gxe_bf[((size_t)(t * 32 + b)) * 1536 + n]);
            }
            wait_vm0();
            const u16* wl = &WxCS[tl * 16 + nl][0];
            f32x4 acc = {0.f, 0.f, 0.f, 0.f};
            #pragma unroll
            for (int i = 0; i < 16; ++i) {
                short8 bfv = *(const short8*)(wl + i * 32 + kq * 8);
                acc = __builtin_amdgcn_mfma_f32_16x16x32_bf16(
                    __builtin_bit_cast(short8, a[i]), bfv, acc, 0, 0, 0);
            }
            if (n < 512) {
                u32 pk[4];
                #pragma unroll
                for (int rr = 0; rr < 4; ++rr) {
                    const float r = sigmoid_f(gxr_pf[rr] + acc[rr] + aPk[rr] + brz[n]);
                    const float hold = bf2f((u16)((n & 1) ? (hvp[rr] >> 16) : (hvp[rr] & 0xFFFF)));
                    pk[rr] = (u32)f2bf(r * hold);
                }
                #pragma unroll
                for (int rr = 0; rr < 4; ++rr) {
                    u32 oth = (u32)__shfl_xor((int)pk[rr], 1);
                    if ((n & 1) == 0) {
                        const int b = bt * 16 + kq * 4 + rr;
                        st_sc1_u32(rhg + b * 256 + (n >> 1), (pk[rr] & 0xFFFF) | (oth << 16));
                    }
                }
            } else if (n < 1024) {
                #pragma unroll
                for (int rr = 0; rr < 4; ++rr) {
                    const int b = bt * 16 + kq * 4 + rr;
                    const float z = sigmoid_f(gxr_pf[rr] + acc[rr] + aPk[rr] + brz[n]);
                    st_sc1_u32(zg + b * 512 + (n - 512), __float_as_uint(z));
                }
            } else {
                #pragma unroll
                for (int rr = 0; rr < 4; ++rr) {
                    const int b = bt * 16 + kq * 4 + rr;
                    st_sc1_u32(gg + b * 512 + (n - 1024), __float_as_uint(gxr_pf[rr] + acc[rr]));
                }
            }
        }
        gbar32(flags, (u32)(4 * t + 3));
        // ---- P4: (r*h)@Un, h update (waves 0..1) ----
        if (v < 2) {
            const int bt = v;
            const int n = w * 16 + nl;
            const int brow = bt * 16 + nl;
            uint4 a[16]; u32 gvp[4], zvp[4], hvp[4];
            const u64* ab = rq + brow * 128 + kq * 2;
            #pragma unroll
            for (int i = 0; i < 16; ++i) ld16_async(a[i], ab + i * 8);
            #pragma unroll
            for (int rr = 0; rr < 4; ++rr) {
                const int b = bt * 16 + kq * 4 + rr;
                ld4_async(gvp[rr], gg + b * 512 + n);
                ld4_async(zvp[rr], zg + b * 512 + n);
                ld4_async(hvp[rr], hgA + b * 256 + (n >> 1));
            }
            wait_vm0();
            const u16* wl = &UnS2[nl][0];
            f32x4 acc = {0.f, 0.f, 0.f, 0.f};
            #pragma unroll
            for (int i = 0; i < 16; ++i) {
                short8 bfv = *(const short8*)(wl + i * 32 + kq * 8);
                acc = __builtin_amdgcn_mfma_f32_16x16x32_bf16(
                    __builtin_bit_cast(short8, a[i]), bfv, acc, 0, 0, 0);
            }
            u32 pk[4];
            #pragma unroll
            for (int rr = 0; rr < 4; ++rr) {
                const int b = bt * 16 + kq * 4 + rr;
                const float nn = tanh_f(__uint_as_float(gvp[rr]) + acc[rr] + bn[n]);
                const float z = __uint_as_float(zvp[rr]);
                const float hold = bf2f((u16)((n & 1) ? (hvp[rr] >> 16) : (hvp[rr] & 0xFFFF)));
                const float hn = (1.f - z) * hold + z * nn;
                pk[rr] = (u32)f2bf(hn);
            }
            #pragma unroll
            for (int rr = 0; rr < 4; ++rr) {
                u32 oth = (u32)__shfl_xor((int)pk[rr], 1);
                if ((n & 1) == 0) {
                    const int b = bt * 16 + kq * 4 + rr;
                    const u32 pr = (pk[rr] & 0xFFFF) | (oth << 16);
                    st_sc1_u32(hgW + b * 256 + (n >> 1), pr);
                    st_sc1_u32((u32*)(hctx + ((size_t)(t * 32 + b)) * 1024 + n), pr);
                }
            }
        }
        gbar32(flags, (u32)(4 * t + 4));
        if (do_gemm && w == 0 && tid == 0) st_sc1_u32(progress, (u32)(t + 1));
    }
    // recurrence done: join the tile workers for the tail
    if (do_gemm)
        gemm_tiles(hctx, outWT, out_b, Cout, progress, tctr, &UWsS[0][0], &wslotS);
}

// ---------------- log_softmax: 2-pass (online max+sum), in-place on [4096, 32000] ----------------
__global__ __launch_bounds__(256) void log_softmax_rows(float* __restrict__ out)
{
    const int row = blockIdx.x, tid = threadIdx.x;
    float* p = out + (size_t)row * VTOK;
    __shared__ float rbM[4], rbS[4];
    const float L2E = 1.442695040888963f;
    float m = -3.0e38f, s = 0.f;
    for (int i = tid * 4; i < VTOK; i += 1024) {
        float4 v = *(const float4*)(p + i);
        float lm = fmaxf(fmaxf(v.x, v.y), fmaxf(v.z, v.w));
        float nm = fmaxf(m, lm);
        s = s * fexp2((m - nm) * L2E)
          + fexp2((v.x - nm) * L2E) + fexp2((v.y - nm) * L2E)
          + fexp2((v.z - nm) * L2E) + fexp2((v.w - nm) * L2E);
        m = nm;
    }
    for (int o = 32; o >= 1; o >>= 1) {
        float om = __shfl_xor(m, o), os = __shfl_xor(s, o);
        float nm = fmaxf(m, om);
        s = s * fexp2((m - nm) * L2E) + os * fexp2((om - nm) * L2E);
        m = nm;
    }
    if ((tid & 63) == 0) { rbM[tid >> 6] = m; rbS[tid >> 6] = s; }
    __syncthreads();
    {
        float fm = fmaxf(fmaxf(rbM[0], rbM[1]), fmaxf(rbM[2], rbM[3]));
        float fs = rbS[0] * fexp2((rbM[0] - fm) * L2E) + rbS[1] * fexp2((rbM[1] - fm) * L2E)
                 + rbS[2] * fexp2((rbM[2] - fm) * L2E) + rbS[3] * fexp2((rbM[3] - fm) * L2E);
        m = fm; s = fs;
    }
    const float lse = m + __builtin_amdgcn_logf(s) * 0.6931471805599453f;
    for (int i = tid * 4; i < VTOK; i += 1024) {
        float4 v = *(const float4*)(p + i);
        v.x -= lse; v.y -= lse; v.z -= lse; v.w -= lse;
        *(float4*)(p + i) = v;
    }
}

// ---------------- host launcher ----------------
extern "C" void kernel_launch(void* const* d_in, const int* in_sizes, int n_in,
                              void* d_out, int out_size, void* d_ws, size_t ws_size,
                              hipStream_t stream)
{
    (void)in_sizes; (void)n_in; (void)out_size;
    const int*   src       = (const int*)  d_in[0];
    const int*   tgt       = (const int*)  d_in[1];
    const float* enc_embed = (const float*)d_in[2];
    const float* enc_Wx    = (const float*)d_in[3];
    const float* enc_bx    = (const float*)d_in[4];
    const float* enc_Urz   = (const float*)d_in[5];
    const float* enc_brz   = (const float*)d_in[6];
    const float* enc_Un    = (const float*)d_in[7];
    const float* enc_bn    = (const float*)d_in[8];
    const float* dec_embed = (const float*)d_in[9];
    const float* dec_Wx    = (const float*)d_in[10];
    const float* dec_bx    = (const float*)d_in[11];
    const float* dec_Urz   = (const float*)d_in[12];
    const float* dec_brz   = (const float*)d_in[13];
    const float* dec_Un    = (const float*)d_in[14];
    const float* dec_bn    = (const float*)d_in[15];
    const float* attn_Wh   = (const float*)d_in[16];
    const float* attn_Ws   = (const float*)d_in[17];
    const float* attn_v    = (const float*)d_in[18];
    const float* out_W     = (const float*)d_in[19];
    const float* out_b     = (const float*)d_in[20];

    // ---- d_out head scratch (dead before any logits write reaches it) ----
    char* ob = (char*)d_out;
    float* gx_enc   = (float*)(ob + 0);               // 25165824
    float* gxe_f32  = (float*)(ob + 25165824);        // 25165824
    float* wh_enc   = (float*)(ob + 50331648);        // 8388608
    u16*   Aenc     = (u16*)(ob + 58720256);          // 4194304
    u16*   Adec     = (u16*)(ob + 62914560);          // 4194304
    u16*   enc_hs   = (u16*)(ob + 67108864);          // 4194304
    u16*   encWxT   = (u16*)(ob + 71303168);          // 1572864
    u16*   decWxET  = (u16*)(ob + 72876032);          // 1572864
    u16*   WhT      = (u16*)(ob + 74448896);          // 524288
    u16*   UrzET    = (u16*)(ob + 74973184);          // 1048576
    u16*   UnET     = (u16*)(ob + 76021760);          // 524288
    u16*   UrzDT    = (u16*)(ob + 76546048);          // 1048576
    u16*   UnDT     = (u16*)(ob + 77594624);          // 524288
    u16*   WsT      = (u16*)(ob + 78118912);          // 524288
    u16*   WxCT     = (u16*)(ob + 78643200);          // 1572864  -> ends 80216064
    // gxe bf16 [t*32+b][1536] in d_out tail (clobber-safe vs in-flight logits writes)
    u16*   gxe_bf   = (u16*)(ob + 511705088);         // 12582912

    // ---- workspace ----
    char* wb = (char*)d_ws;
    u16*  outWT = (u16*)(wb + 0);                     // 65536000
    u16*  hctx  = (u16*)(wb + 65536000);              // 8388608 -> 73924608
    const size_t NEED = 82649088;                     // + wh_bf + spack + comm
    const int overlap = (ws_size >= NEED) ? 1 : 0;

    u16 *wh_bf, *spack; u32 *comm;
    if (overlap) {
        wh_bf = (u16*)(wb + 73924608);                // 4194304
        spack = (u16*)(wb + 78118912);                // 4194304
        comm  = (u32*)(wb + 82313216);                // 335872
    } else {
        comm  = (u32*)(ob + 80216064);                // 335872
        wh_bf = (u16*)(ob + 80551936);                // 4194304
        spack = (u16*)(ob + 84746240);                // 4194304
    }
    u32* hgp  = comm;                                 // 16384 u32 (2 parities)
    u32* ctrl = comm + 16384;                         // 2048 u32
    u32* encF = ctrl;                                 // 512
    u32* decF = ctrl + 512;                           // 512
    u32* prog = ctrl + 1024;
    u32* tctr = ctrl + 1040;
    u32* rhg  = comm + 18432;                         // 8192
    u32* ctxg = comm + 26624;                         // 8192
    u32* zg   = comm + 34816;                         // 16384
    u32* gg   = comm + 51200;                         // 16384
    u32* aWsg = comm + 67584;                         // 16384

    // ---- prep ----
    transpose_cvt<<<dim3(48, 16),   256, 0, stream>>>(enc_Wx,  encWxT, 512, 1536);
    transpose_cvt<<<dim3(48, 16),   256, 0, stream>>>(dec_Wx,  decWxET,512, 1536);
    transpose_cvt<<<dim3(16, 16),   256, 0, stream>>>(attn_Wh, WhT,    512, 512);
    transpose_cvt<<<dim3(1000, 32), 256, 0, stream>>>(out_W,   outWT, 1024, 32000);
    transpose_cvt<<<dim3(32, 16),   256, 0, stream>>>(enc_Urz, UrzET,  512, 1024);
    transpose_cvt<<<dim3(16, 16),   256, 0, stream>>>(enc_Un,  UnET,   512, 512);
    transpose_cvt<<<dim3(32, 16),   256, 0, stream>>>(dec_Urz, UrzDT,  512, 1024);
    transpose_cvt<<<dim3(16, 16),   256, 0, stream>>>(dec_Un,  UnDT,   512, 512);
    transpose_cvt<<<dim3(16, 16),   256, 0, stream>>>(attn_Ws, WsT,    512, 512);
    transpose_cvt<<<dim3(48, 16),   256, 0, stream>>>(dec_Wx + (size_t)512 * 1536, WxCT, 512, 1536);
    gather_emb_bf16<<<4096, 128, 0, stream>>>(src, enc_embed, Aenc);
    gather_emb_bf16<<<4096, 128, 0, stream>>>(tgt, dec_embed, Adec);

    gemm_bf16<<<dim3(12, 32), 256, 0, stream>>>(Aenc, encWxT,  enc_bx, gx_enc,  4096, 1536, 512, 0);
    gemm_bf16<<<dim3(12, 32), 256, 0, stream>>>(Adec, decWxET, dec_bx, gxe_f32, 4096, 1536, 512, 0);
    repack_gxe<<<4096, 192, 0, stream>>>(gxe_f32, gxe_bf);

    init_state<<<32, 512, 0, stream>>>(hgp, ctrl);

    // ---- encoder (persistent, 32 WGs) ----
    {
        void* args[] = { (void*)&gx_enc, (void*)&UrzET, (void*)&UnET, (void*)&enc_brz,
                         (void*)&enc_bn, (void*)&hgp, (void*)&rhg, (void*)&zg,
                         (void*)&enc_hs, (void*)&spack, (void*)&encF };
        hipLaunchCooperativeKernel((void*)enc_coop, dim3(32), dim3(512), args, 0, stream);
    }

    gemm_bf16<<<dim3(4, 32), 256, 0, stream>>>(enc_hs, WhT, nullptr, wh_enc, 4096, 512, 512, 0);
    cvt_f32_bf16<<<1024, 256, 0, stream>>>(wh_enc, wh_bf);

    // ---- decoder (+ in-flight output projection when workspace allows) ----
    {
        float* Cout = (float*)d_out;
        int do_gemm = overlap;
        void* args[] = { (void*)&gxe_bf, (void*)&wh_bf, (void*)&spack, (void*)&attn_v,
                         (void*)&dec_brz, (void*)&dec_bn, (void*)&UrzDT, (void*)&WsT,
                         (void*)&WxCT, (void*)&UnDT, (void*)&hgp, (void*)&rhg, (void*)&ctxg,
                         (void*)&zg, (void*)&gg, (void*)&aWsg, (void*)&hctx, (void*)&decF,
                         (void*)&outWT, (void*)&out_b, (void*)&Cout,
                         (void*)&prog, (void*)&tctr, (void*)&do_gemm };
        hipLaunchCooperativeKernel((void*)dec_coop, dim3(overlap ? 128 : 32), dim3(512),
                                   args, 0, stream);
    }

    // fallback: sequential output projection (row-permuted hctx [t*32+b] -> logits [b*128+t])
    if (!overlap)
        gemm_bf16<<<dim3(250, 32), 256, 0, stream>>>(hctx, outWT, out_b, (float*)d_out,
                                                     4096, VTOK, 1024, 1);

    log_softmax_rows<<<4096, 256, 0, stream>>>((float*)d_out);
}